// Round 1
// baseline (520.451 us; speedup 1.0000x reference)
//
#include <hip/hip_runtime.h>
#include <hip/hip_bf16.h>

#define IN_C 512
#define HID_C 256
#define OUT_C 64

typedef __attribute__((ext_vector_type(8))) short bf16x8;
typedef __attribute__((ext_vector_type(4))) float f32x4;

__device__ __forceinline__ ushort f2bf(float f) {
  __hip_bfloat16 h = __float2bfloat16(f);
  union { __hip_bfloat16 h; ushort u; } v; v.h = h; return v.u;
}
__device__ __forceinline__ float bf2f(ushort u) {
  union { unsigned int i; float f; } v; v.i = ((unsigned int)u) << 16; return v.f;
}

// ---------------- graph preprocessing ----------------

__global__ void init_nodes(float* __restrict__ deg, int* __restrict__ counts, int n) {
  int i = blockIdx.x * 256 + threadIdx.x;
  if (i < n) { deg[i] = 1.0f; counts[i] = 0; }  // 1.0 = self loop
}

__global__ void deg_count(const int* __restrict__ dst, float* __restrict__ deg,
                          int* __restrict__ counts, int E) {
  int e = blockIdx.x * 256 + threadIdx.x;
  if (e >= E) return;
  int d = dst[e];
  atomicAdd(&deg[d], 1.0f);
  atomicAdd(&counts[d], 1);
}

__global__ void finish_dinv(float* __restrict__ deg, int n) {
  int i = blockIdx.x * 256 + threadIdx.x;
  if (i < n) deg[i] = rsqrtf(deg[i]);  // deg >= 1 always
}

// single-block exclusive scan over counts -> offsets[n+1]
__global__ void scan_offsets(const int* __restrict__ counts, int* __restrict__ offsets, int n) {
  const int T = 1024;
  int t = threadIdx.x;
  int chunk = (n + T - 1) / T;
  int lo = t * chunk;
  int hi = lo + chunk; if (hi > n) hi = n; if (lo > n) lo = n;
  int s = 0;
  for (int i = lo; i < hi; ++i) s += counts[i];
  int lane = t & 63, wid = t >> 6;
  int x = s;
#pragma unroll
  for (int off = 1; off < 64; off <<= 1) {
    int y = __shfl_up(x, off);
    if (lane >= off) x += y;
  }
  __shared__ int wsum[16];
  __shared__ int wbase[16];
  if (lane == 63) wsum[wid] = x;
  __syncthreads();
  if (t == 0) {
    int acc = 0;
    for (int w = 0; w < 16; ++w) { wbase[w] = acc; acc += wsum[w]; }
  }
  __syncthreads();
  int base = wbase[wid] + (x - s);
  int run = base;
  for (int i = lo; i < hi; ++i) { offsets[i] = run; run += counts[i]; }
  if (t == T - 1) offsets[n] = wbase[15] + x;
}

__global__ void cursor_copy(const int* __restrict__ offs, int* __restrict__ cur, int n) {
  int i = blockIdx.x * 256 + threadIdx.x;
  if (i < n) cur[i] = offs[i];
}

__global__ void fill_adj(const int* __restrict__ src, const int* __restrict__ dst,
                         int* __restrict__ cur, int* __restrict__ adj, int E) {
  int e = blockIdx.x * 256 + threadIdx.x;
  if (e >= E) return;
  int d = dst[e];
  int pos = atomicAdd(&cur[d], 1);
  adj[pos] = src[e];
}

// W[K][Ncol] fp32 -> Wt[Ncol][K] bf16
__global__ void convert_wt(const float* __restrict__ W, ushort* __restrict__ Wt, int K, int Ncol) {
  int idx = blockIdx.x * 256 + threadIdx.x;
  if (idx >= K * Ncol) return;
  int n = idx / K, k = idx % K;
  Wt[idx] = f2bf(W[(size_t)k * Ncol + n]);
}

// ---------------- GEMMs ----------------

#define LDP 56  // LDS pitch in shorts: 112B, 16B-aligned, ~2-way bank aliasing (free)

// C[M][256] (bf16) = A[M][512] (fp32, converted on the fly) x W1t[256][512] (bf16, n-major)
__global__ __launch_bounds__(256) void gemm1(const float* __restrict__ A,
                                             const ushort* __restrict__ Bt,
                                             ushort* __restrict__ C, int M) {
  __shared__ __align__(16) short As[128 * LDP];
  __shared__ __align__(16) short Bs[128 * LDP];
  int tid = threadIdx.x;
  int m0 = blockIdx.x * 128;
  int n0 = blockIdx.y * 128;
  int lane = tid & 63, wid = tid >> 6;
  int wm = (wid >> 1) * 64, wn = (wid & 1) * 64;
  f32x4 acc[4][4] = {};
  for (int k0 = 0; k0 < IN_C; k0 += 32) {
    // stage A 128x32 fp32 -> bf16
    {
      int tr = tid >> 3;          // 0..31
      int tc = (tid & 7) * 4;     // 0..28
#pragma unroll
      for (int i = 0; i < 4; ++i) {
        int row = tr + i * 32;
        int gm = m0 + row;
        float4 v = make_float4(0.f, 0.f, 0.f, 0.f);
        if (gm < M) v = *(const float4*)(A + (size_t)gm * IN_C + k0 + tc);
        uint2 p;
        p.x = (uint)f2bf(v.x) | ((uint)f2bf(v.y) << 16);
        p.y = (uint)f2bf(v.z) | ((uint)f2bf(v.w) << 16);
        *(uint2*)&As[row * LDP + tc] = p;
      }
    }
    // stage B: Bs[n][k]
    {
#pragma unroll
      for (int i = 0; i < 2; ++i) {
        int chunk = tid + i * 256;        // 0..511
        int row = chunk >> 2;
        int c8 = (chunk & 3) * 8;
        uint4 v = *(const uint4*)(Bt + (size_t)(n0 + row) * IN_C + k0 + c8);
        *(uint4*)&Bs[row * LDP + c8] = v;
      }
    }
    __syncthreads();
    bf16x8 a[4], b[4];
    int kf = (lane >> 4) * 8;
    int rl = lane & 15;
#pragma unroll
    for (int i = 0; i < 4; ++i)
      a[i] = *(const bf16x8*)&As[(wm + i * 16 + rl) * LDP + kf];
#pragma unroll
    for (int j = 0; j < 4; ++j)
      b[j] = *(const bf16x8*)&Bs[(wn + j * 16 + rl) * LDP + kf];
#pragma unroll
    for (int i = 0; i < 4; ++i)
#pragma unroll
      for (int j = 0; j < 4; ++j)
        acc[i][j] = __builtin_amdgcn_mfma_f32_16x16x32_bf16(a[i], b[j], acc[i][j], 0, 0, 0);
    __syncthreads();
  }
  int r4 = (lane >> 4) * 4;
  int cl = lane & 15;
#pragma unroll
  for (int i = 0; i < 4; ++i) {
#pragma unroll
    for (int r = 0; r < 4; ++r) {
      int gr = m0 + wm + i * 16 + r4 + r;
      if (gr < M) {
#pragma unroll
        for (int j = 0; j < 4; ++j) {
          int gc = n0 + wn + j * 16 + cl;
          C[(size_t)gr * HID_C + gc] = f2bf(acc[i][j][r]);
        }
      }
    }
  }
}

// C[M][64] (bf16) = A[M][256] (bf16) x W2t[64][256] (bf16 n-major)
__global__ __launch_bounds__(256) void gemm2(const ushort* __restrict__ A,
                                             const ushort* __restrict__ Bt,
                                             ushort* __restrict__ C, int M) {
  __shared__ __align__(16) short As[128 * LDP];
  __shared__ __align__(16) short Bs[64 * LDP];
  int tid = threadIdx.x;
  int m0 = blockIdx.x * 128;
  int lane = tid & 63, wid = tid >> 6;
  int wm = wid * 32;
  f32x4 acc[2][4] = {};
  for (int k0 = 0; k0 < HID_C; k0 += 32) {
    {
#pragma unroll
      for (int i = 0; i < 2; ++i) {
        int chunk = tid + i * 256;        // 0..511
        int row = chunk >> 2;
        int c8 = (chunk & 3) * 8;
        int gm = m0 + row;
        uint4 v = make_uint4(0u, 0u, 0u, 0u);
        if (gm < M) v = *(const uint4*)(A + (size_t)gm * HID_C + k0 + c8);
        *(uint4*)&As[row * LDP + c8] = v;
      }
    }
    {
      int chunk = tid;                    // 0..255
      int row = chunk >> 2;
      int c8 = (chunk & 3) * 8;
      uint4 v = *(const uint4*)(Bt + (size_t)row * HID_C + k0 + c8);
      *(uint4*)&Bs[row * LDP + c8] = v;
    }
    __syncthreads();
    bf16x8 a[2], b[4];
    int kf = (lane >> 4) * 8;
    int rl = lane & 15;
#pragma unroll
    for (int i = 0; i < 2; ++i)
      a[i] = *(const bf16x8*)&As[(wm + i * 16 + rl) * LDP + kf];
#pragma unroll
    for (int j = 0; j < 4; ++j)
      b[j] = *(const bf16x8*)&Bs[(j * 16 + rl) * LDP + kf];
#pragma unroll
    for (int i = 0; i < 2; ++i)
#pragma unroll
      for (int j = 0; j < 4; ++j)
        acc[i][j] = __builtin_amdgcn_mfma_f32_16x16x32_bf16(a[i], b[j], acc[i][j], 0, 0, 0);
    __syncthreads();
  }
  int r4 = (lane >> 4) * 4;
  int cl = lane & 15;
#pragma unroll
  for (int i = 0; i < 2; ++i) {
#pragma unroll
    for (int r = 0; r < 4; ++r) {
      int gr = m0 + wm + i * 16 + r4 + r;
      if (gr < M) {
#pragma unroll
        for (int j = 0; j < 4; ++j) {
          int gc = j * 16 + cl;
          C[(size_t)gr * OUT_C + gc] = f2bf(acc[i][j][r]);
        }
      }
    }
  }
}

// ---------------- aggregation ----------------

// out[v] = relu( sum_{e,self} w * h[s] + b1 ), 256 channels, one wave per node
__global__ __launch_bounds__(256) void agg1(const ushort* __restrict__ h,
                                            ushort* __restrict__ out,
                                            const float* __restrict__ dinv,
                                            const int* __restrict__ offs,
                                            const int* __restrict__ adj,
                                            const float* __restrict__ bias, int Nn) {
  int node = blockIdx.x * 4 + (threadIdx.x >> 6);
  if (node >= Nn) return;
  int lane = threadIdx.x & 63;
  int c0 = lane * 4;
  float dv = dinv[node];
  float a0, a1, a2, a3;
  {
    uint2 u = *(const uint2*)&h[(size_t)node * HID_C + c0];
    float w = dv * dv;
    a0 = w * bf2f((ushort)u.x);  a1 = w * bf2f((ushort)(u.x >> 16));
    a2 = w * bf2f((ushort)u.y);  a3 = w * bf2f((ushort)(u.y >> 16));
  }
  int e0 = offs[node], e1 = offs[node + 1];
  for (int e = e0; e < e1; ++e) {
    int s = adj[e];
    float w = dv * dinv[s];
    uint2 u = *(const uint2*)&h[(size_t)s * HID_C + c0];
    a0 += w * bf2f((ushort)u.x);  a1 += w * bf2f((ushort)(u.x >> 16));
    a2 += w * bf2f((ushort)u.y);  a3 += w * bf2f((ushort)(u.y >> 16));
  }
  float4 bb = *(const float4*)&bias[c0];
  a0 = fmaxf(a0 + bb.x, 0.f);
  a1 = fmaxf(a1 + bb.y, 0.f);
  a2 = fmaxf(a2 + bb.z, 0.f);
  a3 = fmaxf(a3 + bb.w, 0.f);
  uint2 p;
  p.x = (uint)f2bf(a0) | ((uint)f2bf(a1) << 16);
  p.y = (uint)f2bf(a2) | ((uint)f2bf(a3) << 16);
  *(uint2*)&out[(size_t)node * HID_C + c0] = p;
}

// out[v] = log_softmax( sum w*h[s] + b2 ), 64 channels = 64 lanes, one wave per node
__global__ __launch_bounds__(256) void agg2(const ushort* __restrict__ h,
                                            float* __restrict__ out,
                                            const float* __restrict__ dinv,
                                            const int* __restrict__ offs,
                                            const int* __restrict__ adj,
                                            const float* __restrict__ bias, int Nn) {
  int node = blockIdx.x * 4 + (threadIdx.x >> 6);
  if (node >= Nn) return;
  int lane = threadIdx.x & 63;
  float dv = dinv[node];
  float acc = dv * dv * bf2f(h[(size_t)node * OUT_C + lane]);
  int e0 = offs[node], e1 = offs[node + 1];
  for (int e = e0; e < e1; ++e) {
    int s = adj[e];
    acc += dv * dinv[s] * bf2f(h[(size_t)s * OUT_C + lane]);
  }
  float v = acc + bias[lane];
  float m = v;
#pragma unroll
  for (int off = 32; off > 0; off >>= 1) m = fmaxf(m, __shfl_xor(m, off));
  float ex = expf(v - m);
  float ssum = ex;
#pragma unroll
  for (int off = 32; off > 0; off >>= 1) ssum += __shfl_xor(ssum, off);
  out[(size_t)node * OUT_C + lane] = (v - m) - logf(ssum);
}

// ---------------- launch ----------------

extern "C" void kernel_launch(void* const* d_in, const int* in_sizes, int n_in,
                              void* d_out, int out_size, void* d_ws, size_t ws_size,
                              hipStream_t stream) {
  const float* x  = (const float*)d_in[0];
  const int*   ei = (const int*)d_in[1];
  const float* W1 = (const float*)d_in[2];
  const float* b1 = (const float*)d_in[3];
  const float* W2 = (const float*)d_in[4];
  const float* b2 = (const float*)d_in[5];
  float* outp = (float*)d_out;

  int Nn = in_sizes[0] / IN_C;
  int E  = in_sizes[1] / 2;
  const int* srcv = ei;
  const int* dstv = ei + E;

  char* ws = (char*)d_ws;
  size_t o = 0;
  auto alloc = [&](size_t bytes) {
    char* p = ws + o;
    o = (o + bytes + 255) & ~(size_t)255;
    return p;
  };
  float*  dinv  = (float*)alloc((size_t)Nn * 4);
  int*    counts= (int*)alloc((size_t)Nn * 4);
  int*    offs  = (int*)alloc((size_t)(Nn + 1) * 4);
  int*    cur   = (int*)alloc((size_t)Nn * 4);
  int*    adj   = (int*)alloc((size_t)E * 4);
  ushort* W1t   = (ushort*)alloc((size_t)IN_C * HID_C * 2);
  ushort* W2t   = (ushort*)alloc((size_t)HID_C * OUT_C * 2);
  ushort* h1    = (ushort*)alloc((size_t)Nn * HID_C * 2);
  ushort* h1a   = (ushort*)alloc((size_t)Nn * HID_C * 2);
  ushort* h2    = (ushort*)alloc((size_t)Nn * OUT_C * 2);

  int nb = (Nn + 255) / 256;
  int eb = (E + 255) / 256;

  init_nodes<<<nb, 256, 0, stream>>>(dinv, counts, Nn);
  deg_count<<<eb, 256, 0, stream>>>(dstv, dinv, counts, E);
  finish_dinv<<<nb, 256, 0, stream>>>(dinv, Nn);
  scan_offsets<<<1, 1024, 0, stream>>>(counts, offs, Nn);
  cursor_copy<<<nb, 256, 0, stream>>>(offs, cur, Nn);
  fill_adj<<<eb, 256, 0, stream>>>(srcv, dstv, cur, adj, E);
  convert_wt<<<(IN_C * HID_C + 255) / 256, 256, 0, stream>>>(W1, W1t, IN_C, HID_C);
  convert_wt<<<(HID_C * OUT_C + 255) / 256, 256, 0, stream>>>(W2, W2t, HID_C, OUT_C);

  gemm1<<<dim3((Nn + 127) / 128, HID_C / 128), 256, 0, stream>>>(x, W1t, h1, Nn);
  agg1<<<(Nn + 3) / 4, 256, 0, stream>>>(h1, h1a, dinv, offs, adj, b1, Nn);
  gemm2<<<(Nn + 127) / 128, 256, 0, stream>>>(h1a, W2t, h2, Nn);
  agg2<<<(Nn + 3) / 4, 256, 0, stream>>>(h2, outp, dinv, offs, adj, b2, Nn);
}

// Round 2
// 404.982 us; speedup vs baseline: 1.2851x; 1.2851x over previous
//
#include <hip/hip_runtime.h>
#include <hip/hip_bf16.h>

#define IN_C 512
#define HID_C 256
#define OUT_C 64

typedef __attribute__((ext_vector_type(8))) short bf16x8;
typedef __attribute__((ext_vector_type(4))) float f32x4;

__device__ __forceinline__ ushort f2bf(float f) {
  __hip_bfloat16 h = __float2bfloat16(f);
  union { __hip_bfloat16 h; ushort u; } v; v.h = h; return v.u;
}
__device__ __forceinline__ void acc2(float& lo, float& hi, uint u) {
  union { uint i; float f; } a, b;
  a.i = u << 16; b.i = u & 0xffff0000u;
  lo += a.f; hi += b.f;
}

// ---------------- graph preprocessing ----------------

__global__ void deg_count(const int* __restrict__ dst, int* __restrict__ counts, int E) {
  int e = blockIdx.x * 256 + threadIdx.x;
  if (e >= E) return;
  atomicAdd(&counts[dst[e]], 1);
}

// single-block exclusive scan over counts -> offsets[n+1], cursors, dinv
__global__ void scan_offsets(const int* __restrict__ counts, int* __restrict__ offsets,
                             int* __restrict__ cur, float* __restrict__ dinv, int n) {
  const int T = 1024;
  int t = threadIdx.x;
  int chunk = (n + T - 1) / T;
  int lo = t * chunk;
  int hi = lo + chunk; if (hi > n) hi = n; if (lo > n) lo = n;
  int s = 0;
  for (int i = lo; i < hi; ++i) s += counts[i];
  int lane = t & 63, wid = t >> 6;
  int x = s;
#pragma unroll
  for (int off = 1; off < 64; off <<= 1) {
    int y = __shfl_up(x, off);
    if (lane >= off) x += y;
  }
  __shared__ int wsum[16];
  __shared__ int wbase[16];
  if (lane == 63) wsum[wid] = x;
  __syncthreads();
  if (t == 0) {
    int acc = 0;
    for (int w = 0; w < 16; ++w) { wbase[w] = acc; acc += wsum[w]; }
  }
  __syncthreads();
  int base = wbase[wid] + (x - s);
  int run = base;
  for (int i = lo; i < hi; ++i) {
    offsets[i] = run;
    cur[i] = run;
    dinv[i] = rsqrtf((float)(counts[i] + 1));
    run += counts[i];
  }
  if (t == T - 1) offsets[n] = wbase[15] + x;
}

__global__ void fill_adj(const int* __restrict__ src, const int* __restrict__ dst,
                         int* __restrict__ cur, int* __restrict__ adj, int E) {
  int e = blockIdx.x * 256 + threadIdx.x;
  if (e >= E) return;
  int pos = atomicAdd(&cur[dst[e]], 1);
  adj[pos] = src[e];
}

// W[K][Ncol] fp32 -> Wt[Ncol][K] bf16
__global__ void convert_wt(const float* __restrict__ W, ushort* __restrict__ Wt, int K, int Ncol) {
  int idx = blockIdx.x * 256 + threadIdx.x;
  if (idx >= K * Ncol) return;
  int n = idx / K, k = idx % K;
  Wt[idx] = f2bf(W[(size_t)k * Ncol + n]);
}

// ---------------- GEMMs ----------------

#define LDP 56  // LDS pitch in shorts: 112B, 16B-aligned, ~2-way bank aliasing (free)

// C[M][256] (bf16, pre-scaled by dinv[row]) = A[M][512] fp32 x W1t[256][512] bf16
__global__ __launch_bounds__(256) void gemm1(const float* __restrict__ A,
                                             const ushort* __restrict__ Bt,
                                             const float* __restrict__ dinv,
                                             ushort* __restrict__ C, int M) {
  __shared__ __align__(16) short As[128 * LDP];
  __shared__ __align__(16) short Bs[128 * LDP];
  int tid = threadIdx.x;
  int m0 = blockIdx.x * 128;
  int n0 = blockIdx.y * 128;
  int lane = tid & 63, wid = tid >> 6;
  int wm = (wid >> 1) * 64, wn = (wid & 1) * 64;
  f32x4 acc[4][4] = {};
  for (int k0 = 0; k0 < IN_C; k0 += 32) {
    {
      int tr = tid >> 3;
      int tc = (tid & 7) * 4;
#pragma unroll
      for (int i = 0; i < 4; ++i) {
        int row = tr + i * 32;
        int gm = m0 + row;
        float4 v = make_float4(0.f, 0.f, 0.f, 0.f);
        if (gm < M) v = *(const float4*)(A + (size_t)gm * IN_C + k0 + tc);
        uint2 p;
        p.x = (uint)f2bf(v.x) | ((uint)f2bf(v.y) << 16);
        p.y = (uint)f2bf(v.z) | ((uint)f2bf(v.w) << 16);
        *(uint2*)&As[row * LDP + tc] = p;
      }
    }
    {
#pragma unroll
      for (int i = 0; i < 2; ++i) {
        int chunk = tid + i * 256;
        int row = chunk >> 2;
        int c8 = (chunk & 3) * 8;
        uint4 v = *(const uint4*)(Bt + (size_t)(n0 + row) * IN_C + k0 + c8);
        *(uint4*)&Bs[row * LDP + c8] = v;
      }
    }
    __syncthreads();
    bf16x8 a[4], b[4];
    int kf = (lane >> 4) * 8;
    int rl = lane & 15;
#pragma unroll
    for (int i = 0; i < 4; ++i)
      a[i] = *(const bf16x8*)&As[(wm + i * 16 + rl) * LDP + kf];
#pragma unroll
    for (int j = 0; j < 4; ++j)
      b[j] = *(const bf16x8*)&Bs[(wn + j * 16 + rl) * LDP + kf];
#pragma unroll
    for (int i = 0; i < 4; ++i)
#pragma unroll
      for (int j = 0; j < 4; ++j)
        acc[i][j] = __builtin_amdgcn_mfma_f32_16x16x32_bf16(a[i], b[j], acc[i][j], 0, 0, 0);
    __syncthreads();
  }
  int r4 = (lane >> 4) * 4;
  int cl = lane & 15;
#pragma unroll
  for (int i = 0; i < 4; ++i) {
#pragma unroll
    for (int r = 0; r < 4; ++r) {
      int gr = m0 + wm + i * 16 + r4 + r;
      if (gr < M) {
        float dv = dinv[gr];
#pragma unroll
        for (int j = 0; j < 4; ++j) {
          int gc = n0 + wn + j * 16 + cl;
          C[(size_t)gr * HID_C + gc] = f2bf(dv * acc[i][j][r]);
        }
      }
    }
  }
}

// C[M][64] (bf16, pre-scaled by dinv[row]) = A[M][256] bf16 x W2t[64][256] bf16
__global__ __launch_bounds__(256) void gemm2(const ushort* __restrict__ A,
                                             const ushort* __restrict__ Bt,
                                             const float* __restrict__ dinv,
                                             ushort* __restrict__ C, int M) {
  __shared__ __align__(16) short As[128 * LDP];
  __shared__ __align__(16) short Bs[64 * LDP];
  int tid = threadIdx.x;
  int m0 = blockIdx.x * 128;
  int lane = tid & 63, wid = tid >> 6;
  int wm = wid * 32;
  f32x4 acc[2][4] = {};
  for (int k0 = 0; k0 < HID_C; k0 += 32) {
    {
#pragma unroll
      for (int i = 0; i < 2; ++i) {
        int chunk = tid + i * 256;
        int row = chunk >> 2;
        int c8 = (chunk & 3) * 8;
        int gm = m0 + row;
        uint4 v = make_uint4(0u, 0u, 0u, 0u);
        if (gm < M) v = *(const uint4*)(A + (size_t)gm * HID_C + k0 + c8);
        *(uint4*)&As[row * LDP + c8] = v;
      }
    }
    {
      int chunk = tid;
      int row = chunk >> 2;
      int c8 = (chunk & 3) * 8;
      uint4 v = *(const uint4*)(Bt + (size_t)row * HID_C + k0 + c8);
      *(uint4*)&Bs[row * LDP + c8] = v;
    }
    __syncthreads();
    bf16x8 a[2], b[4];
    int kf = (lane >> 4) * 8;
    int rl = lane & 15;
#pragma unroll
    for (int i = 0; i < 2; ++i)
      a[i] = *(const bf16x8*)&As[(wm + i * 16 + rl) * LDP + kf];
#pragma unroll
    for (int j = 0; j < 4; ++j)
      b[j] = *(const bf16x8*)&Bs[(j * 16 + rl) * LDP + kf];
#pragma unroll
    for (int i = 0; i < 2; ++i)
#pragma unroll
      for (int j = 0; j < 4; ++j)
        acc[i][j] = __builtin_amdgcn_mfma_f32_16x16x32_bf16(a[i], b[j], acc[i][j], 0, 0, 0);
    __syncthreads();
  }
  int r4 = (lane >> 4) * 4;
  int cl = lane & 15;
#pragma unroll
  for (int i = 0; i < 2; ++i) {
#pragma unroll
    for (int r = 0; r < 4; ++r) {
      int gr = m0 + wm + i * 16 + r4 + r;
      if (gr < M) {
        float dv = dinv[gr];
#pragma unroll
        for (int j = 0; j < 4; ++j) {
          int gc = j * 16 + cl;
          C[(size_t)gr * OUT_C + gc] = f2bf(dv * acc[i][j][r]);
        }
      }
    }
  }
}

// ---------------- aggregation ----------------

// h = pre-scaled h1p (dinv[v]*XW1). out[v] = relu(dinv[v] * sum_{s in N(v)+self} h[s] + b1)
// one wave per node; 4 edge slots x 16 lanes x 16 channels (32B per lane)
__global__ __launch_bounds__(256) void agg1(const ushort* __restrict__ h,
                                            ushort* __restrict__ out,
                                            const float* __restrict__ dinv,
                                            const int* __restrict__ offs,
                                            const int* __restrict__ adj,
                                            const float* __restrict__ bias, int Nn) {
  int node = blockIdx.x * 4 + (threadIdx.x >> 6);
  if (node >= Nn) return;
  int lane = threadIdx.x & 63;
  int slot = lane >> 4;            // 0..3
  int c0 = (lane & 15) * 16;       // 16 channels per lane
  int e0 = offs[node];
  int cnt = offs[node + 1] - e0 + 1;  // virtual edge 0 = self loop
  float a[16];
#pragma unroll
  for (int i = 0; i < 16; ++i) a[i] = 0.f;
  for (int k = slot; k < cnt; k += 4) {
    int s = (k == 0) ? node : adj[e0 + k - 1];
    const uint4* rp = (const uint4*)(h + (size_t)s * HID_C + c0);
    uint4 u0 = rp[0];
    uint4 u1 = rp[1];
    acc2(a[0],  a[1],  u0.x);
    acc2(a[2],  a[3],  u0.y);
    acc2(a[4],  a[5],  u0.z);
    acc2(a[6],  a[7],  u0.w);
    acc2(a[8],  a[9],  u1.x);
    acc2(a[10], a[11], u1.y);
    acc2(a[12], a[13], u1.z);
    acc2(a[14], a[15], u1.w);
  }
#pragma unroll
  for (int i = 0; i < 16; ++i) {
    a[i] += __shfl_xor(a[i], 16);
    a[i] += __shfl_xor(a[i], 32);
  }
  if (lane < 16) {
    float dv = dinv[node];
    const float4* bp = (const float4*)(bias + c0);
    float bb[16];
#pragma unroll
    for (int q = 0; q < 4; ++q) {
      float4 b4 = bp[q];
      bb[q * 4 + 0] = b4.x; bb[q * 4 + 1] = b4.y;
      bb[q * 4 + 2] = b4.z; bb[q * 4 + 3] = b4.w;
    }
    uint r[8];
#pragma unroll
    for (int i = 0; i < 8; ++i) {
      float v0 = fmaxf(dv * a[2 * i]     + bb[2 * i],     0.f);
      float v1 = fmaxf(dv * a[2 * i + 1] + bb[2 * i + 1], 0.f);
      r[i] = (uint)f2bf(v0) | ((uint)f2bf(v1) << 16);
    }
    uint4* op = (uint4*)(out + (size_t)node * HID_C + c0);
    op[0] = make_uint4(r[0], r[1], r[2], r[3]);
    op[1] = make_uint4(r[4], r[5], r[6], r[7]);
  }
}

// h = pre-scaled h2p. out[v] = log_softmax(dinv[v]*sum h[s] + b2)
// one wave per node; 8 edge slots x 8 lanes x 8 channels (16B per lane)
__global__ __launch_bounds__(256) void agg2(const ushort* __restrict__ h,
                                            float* __restrict__ out,
                                            const float* __restrict__ dinv,
                                            const int* __restrict__ offs,
                                            const int* __restrict__ adj,
                                            const float* __restrict__ bias, int Nn) {
  int node = blockIdx.x * 4 + (threadIdx.x >> 6);
  if (node >= Nn) return;
  int lane = threadIdx.x & 63;
  int slot = lane >> 3;            // 0..7
  int c0 = (lane & 7) * 8;         // 8 channels per lane
  int e0 = offs[node];
  int cnt = offs[node + 1] - e0 + 1;
  float a[8];
#pragma unroll
  for (int i = 0; i < 8; ++i) a[i] = 0.f;
  for (int k = slot; k < cnt; k += 8) {
    int s = (k == 0) ? node : adj[e0 + k - 1];
    uint4 u = *(const uint4*)(h + (size_t)s * OUT_C + c0);
    acc2(a[0], a[1], u.x);
    acc2(a[2], a[3], u.y);
    acc2(a[4], a[5], u.z);
    acc2(a[6], a[7], u.w);
  }
#pragma unroll
  for (int i = 0; i < 8; ++i) {
    a[i] += __shfl_xor(a[i], 8);
    a[i] += __shfl_xor(a[i], 16);
    a[i] += __shfl_xor(a[i], 32);
  }
  float dv = dinv[node];
  const float4* bp = (const float4*)(bias + c0);
  float4 bb0 = bp[0], bb1 = bp[1];
  float v[8];
  v[0] = dv * a[0] + bb0.x; v[1] = dv * a[1] + bb0.y;
  v[2] = dv * a[2] + bb0.z; v[3] = dv * a[3] + bb0.w;
  v[4] = dv * a[4] + bb1.x; v[5] = dv * a[5] + bb1.y;
  v[6] = dv * a[6] + bb1.z; v[7] = dv * a[7] + bb1.w;
  float m = v[0];
#pragma unroll
  for (int i = 1; i < 8; ++i) m = fmaxf(m, v[i]);
  m = fmaxf(m, __shfl_xor(m, 1));
  m = fmaxf(m, __shfl_xor(m, 2));
  m = fmaxf(m, __shfl_xor(m, 4));
  float s8 = 0.f;
#pragma unroll
  for (int i = 0; i < 8; ++i) s8 += expf(v[i] - m);
  s8 += __shfl_xor(s8, 1);
  s8 += __shfl_xor(s8, 2);
  s8 += __shfl_xor(s8, 4);
  float lg = logf(s8);
  if (lane < 8) {
    float4* op = (float4*)(out + (size_t)node * OUT_C + c0);
    op[0] = make_float4(v[0] - m - lg, v[1] - m - lg, v[2] - m - lg, v[3] - m - lg);
    op[1] = make_float4(v[4] - m - lg, v[5] - m - lg, v[6] - m - lg, v[7] - m - lg);
  }
}

// ---------------- launch ----------------

extern "C" void kernel_launch(void* const* d_in, const int* in_sizes, int n_in,
                              void* d_out, int out_size, void* d_ws, size_t ws_size,
                              hipStream_t stream) {
  const float* x  = (const float*)d_in[0];
  const int*   ei = (const int*)d_in[1];
  const float* W1 = (const float*)d_in[2];
  const float* b1 = (const float*)d_in[3];
  const float* W2 = (const float*)d_in[4];
  const float* b2 = (const float*)d_in[5];
  float* outp = (float*)d_out;

  int Nn = in_sizes[0] / IN_C;
  int E  = in_sizes[1] / 2;
  const int* srcv = ei;
  const int* dstv = ei + E;

  char* ws = (char*)d_ws;
  size_t o = 0;
  auto alloc = [&](size_t bytes) {
    char* p = ws + o;
    o = (o + bytes + 255) & ~(size_t)255;
    return p;
  };
  float*  dinv  = (float*)alloc((size_t)Nn * 4);
  int*    counts= (int*)alloc((size_t)Nn * 4);
  int*    offs  = (int*)alloc((size_t)(Nn + 1) * 4);
  int*    cur   = (int*)alloc((size_t)Nn * 4);
  int*    adj   = (int*)alloc((size_t)E * 4);
  ushort* W1t   = (ushort*)alloc((size_t)IN_C * HID_C * 2);
  ushort* W2t   = (ushort*)alloc((size_t)HID_C * OUT_C * 2);
  ushort* h1p   = (ushort*)alloc((size_t)Nn * HID_C * 2);
  ushort* h1a   = (ushort*)alloc((size_t)Nn * HID_C * 2);
  ushort* h2p   = (ushort*)alloc((size_t)Nn * OUT_C * 2);

  int eb = (E + 255) / 256;

  hipMemsetAsync(counts, 0, (size_t)Nn * 4, stream);
  deg_count<<<eb, 256, 0, stream>>>(dstv, counts, E);
  scan_offsets<<<1, 1024, 0, stream>>>(counts, offs, cur, dinv, Nn);
  fill_adj<<<eb, 256, 0, stream>>>(srcv, dstv, cur, adj, E);
  convert_wt<<<(IN_C * HID_C + 255) / 256, 256, 0, stream>>>(W1, W1t, IN_C, HID_C);
  convert_wt<<<(HID_C * OUT_C + 255) / 256, 256, 0, stream>>>(W2, W2t, HID_C, OUT_C);

  gemm1<<<dim3((Nn + 127) / 128, HID_C / 128), 256, 0, stream>>>(x, W1t, dinv, h1p, Nn);
  agg1<<<(Nn + 3) / 4, 256, 0, stream>>>(h1p, h1a, dinv, offs, adj, b1, Nn);
  gemm2<<<(Nn + 127) / 128, 256, 0, stream>>>(h1a, W2t, dinv, h2p, Nn);
  agg2<<<(Nn + 3) / 4, 256, 0, stream>>>(h2p, outp, dinv, offs, adj, b2, Nn);
}

// Round 3
// 278.970 us; speedup vs baseline: 1.8656x; 1.4517x over previous
//
#include <hip/hip_runtime.h>
#include <hip/hip_bf16.h>

#define IN_C 512
#define HID_C 256
#define OUT_C 64

typedef __attribute__((ext_vector_type(8))) short bf16x8;
typedef __attribute__((ext_vector_type(4))) float f32x4;

__device__ __forceinline__ ushort f2bf(float f) {
  __hip_bfloat16 h = __float2bfloat16(f);
  union { __hip_bfloat16 h; ushort u; } v; v.h = h; return v.u;
}
__device__ __forceinline__ void acc2(float& lo, float& hi, uint u) {
  union { uint i; float f; } a, b;
  a.i = u << 16; b.i = u & 0xffff0000u;
  lo += a.f; hi += b.f;
}

// ---------------- graph preprocessing ----------------

__global__ void deg_count(const int* __restrict__ dst, int* __restrict__ counts, int E) {
  int e = blockIdx.x * 256 + threadIdx.x;
  if (e >= E) return;
  atomicAdd(&counts[dst[e]], 1);
}

// ---- hierarchical exclusive scan over counts[n] ----
#define SCAN_TILE 1024  // elements per block (256 threads x int4)

// A: per-block sums
__global__ __launch_bounds__(256) void scan_block_sums(const int* __restrict__ counts,
                                                       int* __restrict__ partial, int n) {
  int base = blockIdx.x * SCAN_TILE + threadIdx.x * 4;
  int s = 0;
  if (base + 3 < n) {
    int4 v = *(const int4*)(counts + base);
    s = v.x + v.y + v.z + v.w;
  } else {
#pragma unroll
    for (int i = 0; i < 4; ++i) if (base + i < n) s += counts[base + i];
  }
#pragma unroll
  for (int off = 1; off < 64; off <<= 1) s += __shfl_xor(s, off);
  __shared__ int ws[4];
  int lane = threadIdx.x & 63, wid = threadIdx.x >> 6;
  if (lane == 0) ws[wid] = s;
  __syncthreads();
  if (threadIdx.x == 0) partial[blockIdx.x] = ws[0] + ws[1] + ws[2] + ws[3];
}

// B: single-wave exclusive scan of partials (carry loop, handles any nb)
__global__ void scan_partials(int* __restrict__ partial, int nb) {
  int lane = threadIdx.x;  // 64 threads
  int carry = 0;
  for (int base = 0; base < nb; base += 64) {
    int i = base + lane;
    int v = (i < nb) ? partial[i] : 0;
    int incl = v;
#pragma unroll
    for (int off = 1; off < 64; off <<= 1) {
      int y = __shfl_up(incl, off);
      if (lane >= off) incl += y;
    }
    if (i < nb) partial[i] = carry + incl - v;
    carry += __shfl(incl, 63);
  }
}

// C: intra-block exclusive scan + base, write offs/cur/dinv
__global__ __launch_bounds__(256) void scan_write(const int* __restrict__ counts,
                                                  const int* __restrict__ partial,
                                                  int* __restrict__ offs,
                                                  int* __restrict__ cur,
                                                  float* __restrict__ dinv,
                                                  int n, int E) {
  int tid = threadIdx.x;
  int base = blockIdx.x * SCAN_TILE + tid * 4;
  int4 c = make_int4(0, 0, 0, 0);
  if (base + 3 < n) {
    c = *(const int4*)(counts + base);
  } else {
    if (base + 0 < n) c.x = counts[base + 0];
    if (base + 1 < n) c.y = counts[base + 1];
    if (base + 2 < n) c.z = counts[base + 2];
  }
  int tsum = c.x + c.y + c.z + c.w;
  int lane = tid & 63, wid = tid >> 6;
  int incl = tsum;
#pragma unroll
  for (int off = 1; off < 64; off <<= 1) {
    int y = __shfl_up(incl, off);
    if (lane >= off) incl += y;
  }
  __shared__ int ws[4];
  if (lane == 63) ws[wid] = incl;
  __syncthreads();
  int wbase = 0;
#pragma unroll
  for (int w = 0; w < 4; ++w) if (w < wid) wbase += ws[w];
  int off0 = partial[blockIdx.x] + wbase + (incl - tsum);
  int4 ov;
  ov.x = off0;
  ov.y = off0 + c.x;
  ov.z = off0 + c.x + c.y;
  ov.w = off0 + c.x + c.y + c.z;
  float4 dv;
  dv.x = rsqrtf((float)(c.x + 1));
  dv.y = rsqrtf((float)(c.y + 1));
  dv.z = rsqrtf((float)(c.z + 1));
  dv.w = rsqrtf((float)(c.w + 1));
  if (base + 3 < n) {
    *(int4*)(offs + base) = ov;
    *(int4*)(cur + base) = ov;
    *(float4*)(dinv + base) = dv;
  } else {
    int o4[4] = {ov.x, ov.y, ov.z, ov.w};
    float d4[4] = {dv.x, dv.y, dv.z, dv.w};
    for (int i = 0; i < 4; ++i)
      if (base + i < n) { offs[base + i] = o4[i]; cur[base + i] = o4[i]; dinv[base + i] = d4[i]; }
  }
  if (blockIdx.x == 0 && tid == 0) offs[n] = E;
}

__global__ void fill_adj(const int* __restrict__ src, const int* __restrict__ dst,
                         int* __restrict__ cur, int* __restrict__ adj, int E) {
  int e = blockIdx.x * 256 + threadIdx.x;
  if (e >= E) return;
  int pos = atomicAdd(&cur[dst[e]], 1);
  adj[pos] = src[e];
}

// W[K][Ncol] fp32 -> Wt[Ncol][K] bf16
__global__ void convert_wt(const float* __restrict__ W, ushort* __restrict__ Wt, int K, int Ncol) {
  int idx = blockIdx.x * 256 + threadIdx.x;
  if (idx >= K * Ncol) return;
  int n = idx / K, k = idx % K;
  Wt[idx] = f2bf(W[(size_t)k * Ncol + n]);
}

// ---------------- GEMMs ----------------

#define LDP 56  // LDS pitch in shorts: 112B, 16B-aligned, ~2-way bank aliasing (free)

// C[M][256] (bf16, pre-scaled by dinv[row]) = A[M][512] fp32 x W1t[256][512] bf16
__global__ __launch_bounds__(256) void gemm1(const float* __restrict__ A,
                                             const ushort* __restrict__ Bt,
                                             const float* __restrict__ dinv,
                                             ushort* __restrict__ C, int M) {
  __shared__ __align__(16) short As[128 * LDP];
  __shared__ __align__(16) short Bs[128 * LDP];
  int tid = threadIdx.x;
  int m0 = blockIdx.x * 128;
  int n0 = blockIdx.y * 128;
  int lane = tid & 63, wid = tid >> 6;
  int wm = (wid >> 1) * 64, wn = (wid & 1) * 64;
  f32x4 acc[4][4] = {};
  for (int k0 = 0; k0 < IN_C; k0 += 32) {
    {
      int tr = tid >> 3;
      int tc = (tid & 7) * 4;
#pragma unroll
      for (int i = 0; i < 4; ++i) {
        int row = tr + i * 32;
        int gm = m0 + row;
        float4 v = make_float4(0.f, 0.f, 0.f, 0.f);
        if (gm < M) v = *(const float4*)(A + (size_t)gm * IN_C + k0 + tc);
        uint2 p;
        p.x = (uint)f2bf(v.x) | ((uint)f2bf(v.y) << 16);
        p.y = (uint)f2bf(v.z) | ((uint)f2bf(v.w) << 16);
        *(uint2*)&As[row * LDP + tc] = p;
      }
    }
    {
#pragma unroll
      for (int i = 0; i < 2; ++i) {
        int chunk = tid + i * 256;
        int row = chunk >> 2;
        int c8 = (chunk & 3) * 8;
        uint4 v = *(const uint4*)(Bt + (size_t)(n0 + row) * IN_C + k0 + c8);
        *(uint4*)&Bs[row * LDP + c8] = v;
      }
    }
    __syncthreads();
    bf16x8 a[4], b[4];
    int kf = (lane >> 4) * 8;
    int rl = lane & 15;
#pragma unroll
    for (int i = 0; i < 4; ++i)
      a[i] = *(const bf16x8*)&As[(wm + i * 16 + rl) * LDP + kf];
#pragma unroll
    for (int j = 0; j < 4; ++j)
      b[j] = *(const bf16x8*)&Bs[(wn + j * 16 + rl) * LDP + kf];
#pragma unroll
    for (int i = 0; i < 4; ++i)
#pragma unroll
      for (int j = 0; j < 4; ++j)
        acc[i][j] = __builtin_amdgcn_mfma_f32_16x16x32_bf16(a[i], b[j], acc[i][j], 0, 0, 0);
    __syncthreads();
  }
  int r4 = (lane >> 4) * 4;
  int cl = lane & 15;
#pragma unroll
  for (int i = 0; i < 4; ++i) {
#pragma unroll
    for (int r = 0; r < 4; ++r) {
      int gr = m0 + wm + i * 16 + r4 + r;
      if (gr < M) {
        float dv = dinv[gr];
#pragma unroll
        for (int j = 0; j < 4; ++j) {
          int gc = n0 + wn + j * 16 + cl;
          C[(size_t)gr * HID_C + gc] = f2bf(dv * acc[i][j][r]);
        }
      }
    }
  }
}

// C[M][64] (bf16, pre-scaled by dinv[row]) = A[M][256] bf16 x W2t[64][256] bf16
__global__ __launch_bounds__(256) void gemm2(const ushort* __restrict__ A,
                                             const ushort* __restrict__ Bt,
                                             const float* __restrict__ dinv,
                                             ushort* __restrict__ C, int M) {
  __shared__ __align__(16) short As[128 * LDP];
  __shared__ __align__(16) short Bs[64 * LDP];
  int tid = threadIdx.x;
  int m0 = blockIdx.x * 128;
  int lane = tid & 63, wid = tid >> 6;
  int wm = wid * 32;
  f32x4 acc[2][4] = {};
  for (int k0 = 0; k0 < HID_C; k0 += 32) {
    {
#pragma unroll
      for (int i = 0; i < 2; ++i) {
        int chunk = tid + i * 256;
        int row = chunk >> 2;
        int c8 = (chunk & 3) * 8;
        int gm = m0 + row;
        uint4 v = make_uint4(0u, 0u, 0u, 0u);
        if (gm < M) v = *(const uint4*)(A + (size_t)gm * HID_C + k0 + c8);
        *(uint4*)&As[row * LDP + c8] = v;
      }
    }
    {
      int chunk = tid;
      int row = chunk >> 2;
      int c8 = (chunk & 3) * 8;
      uint4 v = *(const uint4*)(Bt + (size_t)row * HID_C + k0 + c8);
      *(uint4*)&Bs[row * LDP + c8] = v;
    }
    __syncthreads();
    bf16x8 a[2], b[4];
    int kf = (lane >> 4) * 8;
    int rl = lane & 15;
#pragma unroll
    for (int i = 0; i < 2; ++i)
      a[i] = *(const bf16x8*)&As[(wm + i * 16 + rl) * LDP + kf];
#pragma unroll
    for (int j = 0; j < 4; ++j)
      b[j] = *(const bf16x8*)&Bs[(j * 16 + rl) * LDP + kf];
#pragma unroll
    for (int i = 0; i < 2; ++i)
#pragma unroll
      for (int j = 0; j < 4; ++j)
        acc[i][j] = __builtin_amdgcn_mfma_f32_16x16x32_bf16(a[i], b[j], acc[i][j], 0, 0, 0);
    __syncthreads();
  }
  int r4 = (lane >> 4) * 4;
  int cl = lane & 15;
#pragma unroll
  for (int i = 0; i < 2; ++i) {
#pragma unroll
    for (int r = 0; r < 4; ++r) {
      int gr = m0 + wm + i * 16 + r4 + r;
      if (gr < M) {
        float dv = dinv[gr];
#pragma unroll
        for (int j = 0; j < 4; ++j) {
          int gc = j * 16 + cl;
          C[(size_t)gr * OUT_C + gc] = f2bf(dv * acc[i][j][r]);
        }
      }
    }
  }
}

// ---------------- aggregation ----------------

// h = pre-scaled h1p (dinv[v]*XW1). out[v] = relu(dinv[v] * sum_{s in N(v)+self} h[s] + b1)
// one wave per node; 4 edge slots x 16 lanes x 16 channels (32B per lane)
__global__ __launch_bounds__(256) void agg1(const ushort* __restrict__ h,
                                            ushort* __restrict__ out,
                                            const float* __restrict__ dinv,
                                            const int* __restrict__ offs,
                                            const int* __restrict__ adj,
                                            const float* __restrict__ bias, int Nn) {
  int node = blockIdx.x * 4 + (threadIdx.x >> 6);
  if (node >= Nn) return;
  int lane = threadIdx.x & 63;
  int slot = lane >> 4;            // 0..3
  int c0 = (lane & 15) * 16;       // 16 channels per lane
  int e0 = offs[node];
  int cnt = offs[node + 1] - e0 + 1;  // virtual edge 0 = self loop
  float a[16];
#pragma unroll
  for (int i = 0; i < 16; ++i) a[i] = 0.f;
  for (int k = slot; k < cnt; k += 4) {
    int s = (k == 0) ? node : adj[e0 + k - 1];
    const uint4* rp = (const uint4*)(h + (size_t)s * HID_C + c0);
    uint4 u0 = rp[0];
    uint4 u1 = rp[1];
    acc2(a[0],  a[1],  u0.x);
    acc2(a[2],  a[3],  u0.y);
    acc2(a[4],  a[5],  u0.z);
    acc2(a[6],  a[7],  u0.w);
    acc2(a[8],  a[9],  u1.x);
    acc2(a[10], a[11], u1.y);
    acc2(a[12], a[13], u1.z);
    acc2(a[14], a[15], u1.w);
  }
#pragma unroll
  for (int i = 0; i < 16; ++i) {
    a[i] += __shfl_xor(a[i], 16);
    a[i] += __shfl_xor(a[i], 32);
  }
  if (lane < 16) {
    float dv = dinv[node];
    const float4* bp = (const float4*)(bias + c0);
    float bb[16];
#pragma unroll
    for (int q = 0; q < 4; ++q) {
      float4 b4 = bp[q];
      bb[q * 4 + 0] = b4.x; bb[q * 4 + 1] = b4.y;
      bb[q * 4 + 2] = b4.z; bb[q * 4 + 3] = b4.w;
    }
    uint r[8];
#pragma unroll
    for (int i = 0; i < 8; ++i) {
      float v0 = fmaxf(dv * a[2 * i]     + bb[2 * i],     0.f);
      float v1 = fmaxf(dv * a[2 * i + 1] + bb[2 * i + 1], 0.f);
      r[i] = (uint)f2bf(v0) | ((uint)f2bf(v1) << 16);
    }
    uint4* op = (uint4*)(out + (size_t)node * HID_C + c0);
    op[0] = make_uint4(r[0], r[1], r[2], r[3]);
    op[1] = make_uint4(r[4], r[5], r[6], r[7]);
  }
}

// h = pre-scaled h2p. out[v] = log_softmax(dinv[v]*sum h[s] + b2)
// one wave per node; 8 edge slots x 8 lanes x 8 channels (16B per lane)
__global__ __launch_bounds__(256) void agg2(const ushort* __restrict__ h,
                                            float* __restrict__ out,
                                            const float* __restrict__ dinv,
                                            const int* __restrict__ offs,
                                            const int* __restrict__ adj,
                                            const float* __restrict__ bias, int Nn) {
  int node = blockIdx.x * 4 + (threadIdx.x >> 6);
  if (node >= Nn) return;
  int lane = threadIdx.x & 63;
  int slot = lane >> 3;            // 0..7
  int c0 = (lane & 7) * 8;         // 8 channels per lane
  int e0 = offs[node];
  int cnt = offs[node + 1] - e0 + 1;
  float a[8];
#pragma unroll
  for (int i = 0; i < 8; ++i) a[i] = 0.f;
  for (int k = slot; k < cnt; k += 8) {
    int s = (k == 0) ? node : adj[e0 + k - 1];
    uint4 u = *(const uint4*)(h + (size_t)s * OUT_C + c0);
    acc2(a[0], a[1], u.x);
    acc2(a[2], a[3], u.y);
    acc2(a[4], a[5], u.z);
    acc2(a[6], a[7], u.w);
  }
#pragma unroll
  for (int i = 0; i < 8; ++i) {
    a[i] += __shfl_xor(a[i], 8);
    a[i] += __shfl_xor(a[i], 16);
    a[i] += __shfl_xor(a[i], 32);
  }
  float dv = dinv[node];
  const float4* bp = (const float4*)(bias + c0);
  float4 bb0 = bp[0], bb1 = bp[1];
  float v[8];
  v[0] = dv * a[0] + bb0.x; v[1] = dv * a[1] + bb0.y;
  v[2] = dv * a[2] + bb0.z; v[3] = dv * a[3] + bb0.w;
  v[4] = dv * a[4] + bb1.x; v[5] = dv * a[5] + bb1.y;
  v[6] = dv * a[6] + bb1.z; v[7] = dv * a[7] + bb1.w;
  float m = v[0];
#pragma unroll
  for (int i = 1; i < 8; ++i) m = fmaxf(m, v[i]);
  m = fmaxf(m, __shfl_xor(m, 1));
  m = fmaxf(m, __shfl_xor(m, 2));
  m = fmaxf(m, __shfl_xor(m, 4));
  float s8 = 0.f;
#pragma unroll
  for (int i = 0; i < 8; ++i) s8 += expf(v[i] - m);
  s8 += __shfl_xor(s8, 1);
  s8 += __shfl_xor(s8, 2);
  s8 += __shfl_xor(s8, 4);
  float lg = logf(s8);
  if (lane < 8) {
    float4* op = (float4*)(out + (size_t)node * OUT_C + c0);
    op[0] = make_float4(v[0] - m - lg, v[1] - m - lg, v[2] - m - lg, v[3] - m - lg);
    op[1] = make_float4(v[4] - m - lg, v[5] - m - lg, v[6] - m - lg, v[7] - m - lg);
  }
}

// ---------------- launch ----------------

extern "C" void kernel_launch(void* const* d_in, const int* in_sizes, int n_in,
                              void* d_out, int out_size, void* d_ws, size_t ws_size,
                              hipStream_t stream) {
  const float* x  = (const float*)d_in[0];
  const int*   ei = (const int*)d_in[1];
  const float* W1 = (const float*)d_in[2];
  const float* b1 = (const float*)d_in[3];
  const float* W2 = (const float*)d_in[4];
  const float* b2 = (const float*)d_in[5];
  float* outp = (float*)d_out;

  int Nn = in_sizes[0] / IN_C;
  int E  = in_sizes[1] / 2;
  const int* srcv = ei;
  const int* dstv = ei + E;

  char* ws = (char*)d_ws;
  size_t o = 0;
  auto alloc = [&](size_t bytes) {
    char* p = ws + o;
    o = (o + bytes + 255) & ~(size_t)255;
    return p;
  };
  float*  dinv  = (float*)alloc((size_t)Nn * 4);
  int*    counts= (int*)alloc((size_t)Nn * 4);
  int*    offs  = (int*)alloc((size_t)(Nn + 1) * 4);
  int*    cur   = (int*)alloc((size_t)Nn * 4);
  int*    adj   = (int*)alloc((size_t)E * 4);
  int*    partial=(int*)alloc((size_t)((Nn + SCAN_TILE - 1) / SCAN_TILE) * 4);
  ushort* W1t   = (ushort*)alloc((size_t)IN_C * HID_C * 2);
  ushort* W2t   = (ushort*)alloc((size_t)HID_C * OUT_C * 2);
  ushort* h1p   = (ushort*)alloc((size_t)Nn * HID_C * 2);
  ushort* h1a   = (ushort*)alloc((size_t)Nn * HID_C * 2);
  ushort* h2p   = (ushort*)alloc((size_t)Nn * OUT_C * 2);

  int eb = (E + 255) / 256;
  int sb = (Nn + SCAN_TILE - 1) / SCAN_TILE;

  hipMemsetAsync(counts, 0, (size_t)Nn * 4, stream);
  deg_count<<<eb, 256, 0, stream>>>(dstv, counts, E);
  scan_block_sums<<<sb, 256, 0, stream>>>(counts, partial, Nn);
  scan_partials<<<1, 64, 0, stream>>>(partial, sb);
  scan_write<<<sb, 256, 0, stream>>>(counts, partial, offs, cur, dinv, Nn, E);
  fill_adj<<<eb, 256, 0, stream>>>(srcv, dstv, cur, adj, E);
  convert_wt<<<(IN_C * HID_C + 255) / 256, 256, 0, stream>>>(W1, W1t, IN_C, HID_C);
  convert_wt<<<(HID_C * OUT_C + 255) / 256, 256, 0, stream>>>(W2, W2t, HID_C, OUT_C);

  gemm1<<<dim3((Nn + 127) / 128, HID_C / 128), 256, 0, stream>>>(x, W1t, dinv, h1p, Nn);
  agg1<<<(Nn + 3) / 4, 256, 0, stream>>>(h1p, h1a, dinv, offs, adj, b1, Nn);
  gemm2<<<(Nn + 127) / 128, 256, 0, stream>>>(h1a, W2t, dinv, h2p, Nn);
  agg2<<<(Nn + 3) / 4, 256, 0, stream>>>(h2p, outp, dinv, offs, adj, b2, Nn);
}

// Round 4
// 257.072 us; speedup vs baseline: 2.0245x; 1.0852x over previous
//
#include <hip/hip_runtime.h>
#include <hip/hip_bf16.h>

#define IN_C 512
#define HID_C 256
#define OUT_C 64

typedef __attribute__((ext_vector_type(8))) short bf16x8;
typedef __attribute__((ext_vector_type(4))) float f32x4;

__device__ __forceinline__ ushort f2bf(float f) {
  __hip_bfloat16 h = __float2bfloat16(f);
  union { __hip_bfloat16 h; ushort u; } v; v.h = h; return v.u;
}
__device__ __forceinline__ void acc2(float& lo, float& hi, uint u) {
  union { uint i; float f; } a, b;
  a.i = u << 16; b.i = u & 0xffff0000u;
  lo += a.f; hi += b.f;
}
// async global->LDS, 16B per lane. LDS dest must be linear (base + lane*16).
__device__ __forceinline__ void glds16(const ushort* g, ushort* l) {
  __builtin_amdgcn_global_load_lds(
      (const __attribute__((address_space(1))) unsigned int*)(const void*)g,
      (__attribute__((address_space(3))) unsigned int*)(void*)l, 16, 0, 0);
}

// ---------------- graph preprocessing ----------------

__global__ void deg_count(const int* __restrict__ dst, int* __restrict__ counts, int E) {
  int e = blockIdx.x * 256 + threadIdx.x;
  if (e >= E) return;
  atomicAdd(&counts[dst[e]], 1);
}

#define SCAN_TILE 1024

__global__ __launch_bounds__(256) void scan_block_sums(const int* __restrict__ counts,
                                                       int* __restrict__ partial, int n) {
  int base = blockIdx.x * SCAN_TILE + threadIdx.x * 4;
  int s = 0;
  if (base + 3 < n) {
    int4 v = *(const int4*)(counts + base);
    s = v.x + v.y + v.z + v.w;
  } else {
#pragma unroll
    for (int i = 0; i < 4; ++i) if (base + i < n) s += counts[base + i];
  }
#pragma unroll
  for (int off = 1; off < 64; off <<= 1) s += __shfl_xor(s, off);
  __shared__ int ws[4];
  int lane = threadIdx.x & 63, wid = threadIdx.x >> 6;
  if (lane == 0) ws[wid] = s;
  __syncthreads();
  if (threadIdx.x == 0) partial[blockIdx.x] = ws[0] + ws[1] + ws[2] + ws[3];
}

__global__ void scan_partials(int* __restrict__ partial, int nb) {
  int lane = threadIdx.x;
  int carry = 0;
  for (int base = 0; base < nb; base += 64) {
    int i = base + lane;
    int v = (i < nb) ? partial[i] : 0;
    int incl = v;
#pragma unroll
    for (int off = 1; off < 64; off <<= 1) {
      int y = __shfl_up(incl, off);
      if (lane >= off) incl += y;
    }
    if (i < nb) partial[i] = carry + incl - v;
    carry += __shfl(incl, 63);
  }
}

__global__ __launch_bounds__(256) void scan_write(const int* __restrict__ counts,
                                                  const int* __restrict__ partial,
                                                  int* __restrict__ offs,
                                                  int* __restrict__ cur,
                                                  float* __restrict__ dinv,
                                                  int n, int E) {
  int tid = threadIdx.x;
  int base = blockIdx.x * SCAN_TILE + tid * 4;
  int4 c = make_int4(0, 0, 0, 0);
  if (base + 3 < n) {
    c = *(const int4*)(counts + base);
  } else {
    if (base + 0 < n) c.x = counts[base + 0];
    if (base + 1 < n) c.y = counts[base + 1];
    if (base + 2 < n) c.z = counts[base + 2];
  }
  int tsum = c.x + c.y + c.z + c.w;
  int lane = tid & 63, wid = tid >> 6;
  int incl = tsum;
#pragma unroll
  for (int off = 1; off < 64; off <<= 1) {
    int y = __shfl_up(incl, off);
    if (lane >= off) incl += y;
  }
  __shared__ int ws[4];
  if (lane == 63) ws[wid] = incl;
  __syncthreads();
  int wbase = 0;
#pragma unroll
  for (int w = 0; w < 4; ++w) if (w < wid) wbase += ws[w];
  int off0 = partial[blockIdx.x] + wbase + (incl - tsum);
  int4 ov;
  ov.x = off0;
  ov.y = off0 + c.x;
  ov.z = off0 + c.x + c.y;
  ov.w = off0 + c.x + c.y + c.z;
  float4 dv;
  dv.x = rsqrtf((float)(c.x + 1));
  dv.y = rsqrtf((float)(c.y + 1));
  dv.z = rsqrtf((float)(c.z + 1));
  dv.w = rsqrtf((float)(c.w + 1));
  if (base + 3 < n) {
    *(int4*)(offs + base) = ov;
    *(int4*)(cur + base) = ov;
    *(float4*)(dinv + base) = dv;
  } else {
    int o4[4] = {ov.x, ov.y, ov.z, ov.w};
    float d4[4] = {dv.x, dv.y, dv.z, dv.w};
    for (int i = 0; i < 4; ++i)
      if (base + i < n) { offs[base + i] = o4[i]; cur[base + i] = o4[i]; dinv[base + i] = d4[i]; }
  }
  if (blockIdx.x == 0 && tid == 0) offs[n] = E;
}

__global__ void fill_adj(const int* __restrict__ src, const int* __restrict__ dst,
                         int* __restrict__ cur, int* __restrict__ adj, int E) {
  int e = blockIdx.x * 256 + threadIdx.x;
  if (e >= E) return;
  int pos = atomicAdd(&cur[dst[e]], 1);
  adj[pos] = src[e];
}

__global__ void convert_wt(const float* __restrict__ W, ushort* __restrict__ Wt, int K, int Ncol) {
  int idx = blockIdx.x * 256 + threadIdx.x;
  if (idx >= K * Ncol) return;
  int n = idx / K, k = idx % K;
  Wt[idx] = f2bf(W[(size_t)k * Ncol + n]);
}

// x fp32 -> bf16, 8 elems/thread, grid-stride
__global__ __launch_bounds__(256) void convert_x(const float* __restrict__ x,
                                                 ushort* __restrict__ xb, long n8) {
  long stride = (long)gridDim.x * 256;
  for (long i = (long)blockIdx.x * 256 + threadIdx.x; i < n8; i += stride) {
    const float4* p = (const float4*)(x + i * 8);
    float4 v0 = p[0], v1 = p[1];
    uint4 o;
    o.x = (uint)f2bf(v0.x) | ((uint)f2bf(v0.y) << 16);
    o.y = (uint)f2bf(v0.z) | ((uint)f2bf(v0.w) << 16);
    o.z = (uint)f2bf(v1.x) | ((uint)f2bf(v1.y) << 16);
    o.w = (uint)f2bf(v1.z) | ((uint)f2bf(v1.w) << 16);
    *(uint4*)(xb + i * 8) = o;
  }
}

// ---------------- GEMMs (2-phase global_load_lds template) ----------------

// C[M][256] bf16 (pre-scaled by dinv[row]) = A[M][512] bf16 x W1t[256][512] bf16
// 128x128 tile, BK=32, double-buffered LDS, prefetch-before-compute.
__global__ __launch_bounds__(256) void gemm1_bf(const ushort* __restrict__ A,
                                                const ushort* __restrict__ Bt,
                                                const float* __restrict__ dinv,
                                                ushort* __restrict__ C, int M) {
  __shared__ __align__(16) ushort As[2][128 * 32];
  __shared__ __align__(16) ushort Bs[2][128 * 32];
  int tid = threadIdx.x;
  int lane = tid & 63, wid = tid >> 6;
  int m0 = blockIdx.x * 128;
  int n0 = blockIdx.y * 128;
  // staging: tile is 128 rows x 32 k bf16 = 512 chunks of 16B; thread covers
  // chunk ca and ca+256; LDS dest linear (chunk c at short-offset c*8).
  int ca = wid * 64 + lane;
  int rowa0 = ca >> 2, cola0 = (ca & 3) * 8;
  int rowa1 = (ca + 256) >> 2, cola1 = (ca & 3) * 8;
  int gma0 = m0 + rowa0; if (gma0 >= M) gma0 = M - 1;
  int gma1 = m0 + rowa1; if (gma1 >= M) gma1 = M - 1;
  const ushort* gA0 = A + (size_t)gma0 * IN_C + cola0;
  const ushort* gA1 = A + (size_t)gma1 * IN_C + cola1;
  const ushort* gB0 = Bt + (size_t)(n0 + rowa0) * IN_C + cola0;
  const ushort* gB1 = Bt + (size_t)(n0 + rowa1) * IN_C + cola1;

  int wm = (wid >> 1) * 64, wn = (wid & 1) * 64;
  int kf = (lane >> 4) * 8, rl = lane & 15;
  f32x4 acc[4][4] = {};

  // prologue
  glds16(gA0, &As[0][ca * 8]);
  glds16(gA1, &As[0][ca * 8 + 2048]);
  glds16(gB0, &Bs[0][ca * 8]);
  glds16(gB1, &Bs[0][ca * 8 + 2048]);
  __syncthreads();

  int cur = 0;
  for (int t = 0; t < 16; ++t) {
    if (t < 15) {
      int k0 = (t + 1) * 32;
      int nxt = cur ^ 1;
      glds16(gA0 + k0, &As[nxt][ca * 8]);
      glds16(gA1 + k0, &As[nxt][ca * 8 + 2048]);
      glds16(gB0 + k0, &Bs[nxt][ca * 8]);
      glds16(gB1 + k0, &Bs[nxt][ca * 8 + 2048]);
    }
    bf16x8 a[4], b[4];
#pragma unroll
    for (int i = 0; i < 4; ++i)
      a[i] = *(const bf16x8*)&As[cur][(wm + i * 16 + rl) * 32 + kf];
#pragma unroll
    for (int j = 0; j < 4; ++j)
      b[j] = *(const bf16x8*)&Bs[cur][(wn + j * 16 + rl) * 32 + kf];
#pragma unroll
    for (int i = 0; i < 4; ++i)
#pragma unroll
      for (int j = 0; j < 4; ++j)
        acc[i][j] = __builtin_amdgcn_mfma_f32_16x16x32_bf16(a[i], b[j], acc[i][j], 0, 0, 0);
    __syncthreads();  // drains vmcnt(0): prefetched tile ready; reads of cur done
    cur ^= 1;
  }

  int r4 = (lane >> 4) * 4;
  int cl = lane & 15;
#pragma unroll
  for (int i = 0; i < 4; ++i) {
#pragma unroll
    for (int r = 0; r < 4; ++r) {
      int gr = m0 + wm + i * 16 + r4 + r;
      if (gr < M) {
        float dv = dinv[gr];
#pragma unroll
        for (int j = 0; j < 4; ++j) {
          int gc = n0 + wn + j * 16 + cl;
          C[(size_t)gr * HID_C + gc] = f2bf(dv * acc[i][j][r]);
        }
      }
    }
  }
}

// fallback (ws too small for bf16 copy of x): round-3 fp32-A gemm1
#define LDP 56
__global__ __launch_bounds__(256) void gemm1_f32(const float* __restrict__ A,
                                                 const ushort* __restrict__ Bt,
                                                 const float* __restrict__ dinv,
                                                 ushort* __restrict__ C, int M) {
  __shared__ __align__(16) short As[128 * LDP];
  __shared__ __align__(16) short Bs[128 * LDP];
  int tid = threadIdx.x;
  int m0 = blockIdx.x * 128;
  int n0 = blockIdx.y * 128;
  int lane = tid & 63, wid = tid >> 6;
  int wm = (wid >> 1) * 64, wn = (wid & 1) * 64;
  f32x4 acc[4][4] = {};
  for (int k0 = 0; k0 < IN_C; k0 += 32) {
    {
      int tr = tid >> 3;
      int tc = (tid & 7) * 4;
#pragma unroll
      for (int i = 0; i < 4; ++i) {
        int row = tr + i * 32;
        int gm = m0 + row;
        float4 v = make_float4(0.f, 0.f, 0.f, 0.f);
        if (gm < M) v = *(const float4*)(A + (size_t)gm * IN_C + k0 + tc);
        uint2 p;
        p.x = (uint)f2bf(v.x) | ((uint)f2bf(v.y) << 16);
        p.y = (uint)f2bf(v.z) | ((uint)f2bf(v.w) << 16);
        *(uint2*)&As[row * LDP + tc] = p;
      }
    }
    {
#pragma unroll
      for (int i = 0; i < 2; ++i) {
        int chunk = tid + i * 256;
        int row = chunk >> 2;
        int c8 = (chunk & 3) * 8;
        uint4 v = *(const uint4*)(Bt + (size_t)(n0 + row) * IN_C + k0 + c8);
        *(uint4*)&Bs[row * LDP + c8] = v;
      }
    }
    __syncthreads();
    bf16x8 a[4], b[4];
    int kf = (lane >> 4) * 8;
    int rl = lane & 15;
#pragma unroll
    for (int i = 0; i < 4; ++i)
      a[i] = *(const bf16x8*)&As[(wm + i * 16 + rl) * LDP + kf];
#pragma unroll
    for (int j = 0; j < 4; ++j)
      b[j] = *(const bf16x8*)&Bs[(wn + j * 16 + rl) * LDP + kf];
#pragma unroll
    for (int i = 0; i < 4; ++i)
#pragma unroll
      for (int j = 0; j < 4; ++j)
        acc[i][j] = __builtin_amdgcn_mfma_f32_16x16x32_bf16(a[i], b[j], acc[i][j], 0, 0, 0);
    __syncthreads();
  }
  int r4 = (lane >> 4) * 4;
  int cl = lane & 15;
#pragma unroll
  for (int i = 0; i < 4; ++i) {
#pragma unroll
    for (int r = 0; r < 4; ++r) {
      int gr = m0 + wm + i * 16 + r4 + r;
      if (gr < M) {
        float dv = dinv[gr];
#pragma unroll
        for (int j = 0; j < 4; ++j) {
          int gc = n0 + wn + j * 16 + cl;
          C[(size_t)gr * HID_C + gc] = f2bf(dv * acc[i][j][r]);
        }
      }
    }
  }
}

// C[M][64] bf16 (pre-scaled) = A[M][256] bf16 x W2t[64][256] bf16
// 128x64 tile, BK=32, double-buffered, prefetch-before-compute.
__global__ __launch_bounds__(256) void gemm2(const ushort* __restrict__ A,
                                             const ushort* __restrict__ Bt,
                                             const float* __restrict__ dinv,
                                             ushort* __restrict__ C, int M) {
  __shared__ __align__(16) ushort As[2][128 * 32];
  __shared__ __align__(16) ushort Bs[2][64 * 32];
  int tid = threadIdx.x;
  int lane = tid & 63, wid = tid >> 6;
  int m0 = blockIdx.x * 128;
  int ca = wid * 64 + lane;
  int rowa0 = ca >> 2, cola0 = (ca & 3) * 8;
  int rowa1 = (ca + 256) >> 2;
  int gma0 = m0 + rowa0; if (gma0 >= M) gma0 = M - 1;
  int gma1 = m0 + rowa1; if (gma1 >= M) gma1 = M - 1;
  const ushort* gA0 = A + (size_t)gma0 * HID_C + cola0;
  const ushort* gA1 = A + (size_t)gma1 * HID_C + cola0;
  const ushort* gB0 = Bt + (size_t)rowa0 * HID_C + cola0;

  int wm = wid * 32;
  int kf = (lane >> 4) * 8, rl = lane & 15;
  f32x4 acc[2][4] = {};

  glds16(gA0, &As[0][ca * 8]);
  glds16(gA1, &As[0][ca * 8 + 2048]);
  glds16(gB0, &Bs[0][ca * 8]);
  __syncthreads();

  int cur = 0;
  for (int t = 0; t < 8; ++t) {
    if (t < 7) {
      int k0 = (t + 1) * 32;
      int nxt = cur ^ 1;
      glds16(gA0 + k0, &As[nxt][ca * 8]);
      glds16(gA1 + k0, &As[nxt][ca * 8 + 2048]);
      glds16(gB0 + k0, &Bs[nxt][ca * 8]);
    }
    bf16x8 a[2], b[4];
#pragma unroll
    for (int i = 0; i < 2; ++i)
      a[i] = *(const bf16x8*)&As[cur][(wm + i * 16 + rl) * 32 + kf];
#pragma unroll
    for (int j = 0; j < 4; ++j)
      b[j] = *(const bf16x8*)&Bs[cur][(j * 16 + rl) * 32 + kf];
#pragma unroll
    for (int i = 0; i < 2; ++i)
#pragma unroll
      for (int j = 0; j < 4; ++j)
        acc[i][j] = __builtin_amdgcn_mfma_f32_16x16x32_bf16(a[i], b[j], acc[i][j], 0, 0, 0);
    __syncthreads();
    cur ^= 1;
  }

  int r4 = (lane >> 4) * 4;
  int cl = lane & 15;
#pragma unroll
  for (int i = 0; i < 2; ++i) {
#pragma unroll
    for (int r = 0; r < 4; ++r) {
      int gr = m0 + wm + i * 16 + r4 + r;
      if (gr < M) {
        float dv = dinv[gr];
#pragma unroll
        for (int j = 0; j < 4; ++j) {
          int gc = j * 16 + cl;
          C[(size_t)gr * OUT_C + gc] = f2bf(dv * acc[i][j][r]);
        }
      }
    }
  }
}

// ---------------- aggregation ----------------

__global__ __launch_bounds__(256) void agg1(const ushort* __restrict__ h,
                                            ushort* __restrict__ out,
                                            const float* __restrict__ dinv,
                                            const int* __restrict__ offs,
                                            const int* __restrict__ adj,
                                            const float* __restrict__ bias, int Nn) {
  int node = blockIdx.x * 4 + (threadIdx.x >> 6);
  if (node >= Nn) return;
  int lane = threadIdx.x & 63;
  int slot = lane >> 4;
  int c0 = (lane & 15) * 16;
  int e0 = offs[node];
  int cnt = offs[node + 1] - e0 + 1;
  float a[16];
#pragma unroll
  for (int i = 0; i < 16; ++i) a[i] = 0.f;
  for (int k = slot; k < cnt; k += 4) {
    int s = (k == 0) ? node : adj[e0 + k - 1];
    const uint4* rp = (const uint4*)(h + (size_t)s * HID_C + c0);
    uint4 u0 = rp[0];
    uint4 u1 = rp[1];
    acc2(a[0],  a[1],  u0.x);
    acc2(a[2],  a[3],  u0.y);
    acc2(a[4],  a[5],  u0.z);
    acc2(a[6],  a[7],  u0.w);
    acc2(a[8],  a[9],  u1.x);
    acc2(a[10], a[11], u1.y);
    acc2(a[12], a[13], u1.z);
    acc2(a[14], a[15], u1.w);
  }
#pragma unroll
  for (int i = 0; i < 16; ++i) {
    a[i] += __shfl_xor(a[i], 16);
    a[i] += __shfl_xor(a[i], 32);
  }
  if (lane < 16) {
    float dv = dinv[node];
    const float4* bp = (const float4*)(bias + c0);
    float bb[16];
#pragma unroll
    for (int q = 0; q < 4; ++q) {
      float4 b4 = bp[q];
      bb[q * 4 + 0] = b4.x; bb[q * 4 + 1] = b4.y;
      bb[q * 4 + 2] = b4.z; bb[q * 4 + 3] = b4.w;
    }
    uint r[8];
#pragma unroll
    for (int i = 0; i < 8; ++i) {
      float v0 = fmaxf(dv * a[2 * i]     + bb[2 * i],     0.f);
      float v1 = fmaxf(dv * a[2 * i + 1] + bb[2 * i + 1], 0.f);
      r[i] = (uint)f2bf(v0) | ((uint)f2bf(v1) << 16);
    }
    uint4* op = (uint4*)(out + (size_t)node * HID_C + c0);
    op[0] = make_uint4(r[0], r[1], r[2], r[3]);
    op[1] = make_uint4(r[4], r[5], r[6], r[7]);
  }
}

__global__ __launch_bounds__(256) void agg2(const ushort* __restrict__ h,
                                            float* __restrict__ out,
                                            const float* __restrict__ dinv,
                                            const int* __restrict__ offs,
                                            const int* __restrict__ adj,
                                            const float* __restrict__ bias, int Nn) {
  int node = blockIdx.x * 4 + (threadIdx.x >> 6);
  if (node >= Nn) return;
  int lane = threadIdx.x & 63;
  int slot = lane >> 3;
  int c0 = (lane & 7) * 8;
  int e0 = offs[node];
  int cnt = offs[node + 1] - e0 + 1;
  float a[8];
#pragma unroll
  for (int i = 0; i < 8; ++i) a[i] = 0.f;
  for (int k = slot; k < cnt; k += 8) {
    int s = (k == 0) ? node : adj[e0 + k - 1];
    uint4 u = *(const uint4*)(h + (size_t)s * OUT_C + c0);
    acc2(a[0], a[1], u.x);
    acc2(a[2], a[3], u.y);
    acc2(a[4], a[5], u.z);
    acc2(a[6], a[7], u.w);
  }
#pragma unroll
  for (int i = 0; i < 8; ++i) {
    a[i] += __shfl_xor(a[i], 8);
    a[i] += __shfl_xor(a[i], 16);
    a[i] += __shfl_xor(a[i], 32);
  }
  float dv = dinv[node];
  const float4* bp = (const float4*)(bias + c0);
  float4 bb0 = bp[0], bb1 = bp[1];
  float v[8];
  v[0] = dv * a[0] + bb0.x; v[1] = dv * a[1] + bb0.y;
  v[2] = dv * a[2] + bb0.z; v[3] = dv * a[3] + bb0.w;
  v[4] = dv * a[4] + bb1.x; v[5] = dv * a[5] + bb1.y;
  v[6] = dv * a[6] + bb1.z; v[7] = dv * a[7] + bb1.w;
  float m = v[0];
#pragma unroll
  for (int i = 1; i < 8; ++i) m = fmaxf(m, v[i]);
  m = fmaxf(m, __shfl_xor(m, 1));
  m = fmaxf(m, __shfl_xor(m, 2));
  m = fmaxf(m, __shfl_xor(m, 4));
  float s8 = 0.f;
#pragma unroll
  for (int i = 0; i < 8; ++i) s8 += expf(v[i] - m);
  s8 += __shfl_xor(s8, 1);
  s8 += __shfl_xor(s8, 2);
  s8 += __shfl_xor(s8, 4);
  float lg = logf(s8);
  if (lane < 8) {
    float4* op = (float4*)(out + (size_t)node * OUT_C + c0);
    op[0] = make_float4(v[0] - m - lg, v[1] - m - lg, v[2] - m - lg, v[3] - m - lg);
    op[1] = make_float4(v[4] - m - lg, v[5] - m - lg, v[6] - m - lg, v[7] - m - lg);
  }
}

// ---------------- launch ----------------

extern "C" void kernel_launch(void* const* d_in, const int* in_sizes, int n_in,
                              void* d_out, int out_size, void* d_ws, size_t ws_size,
                              hipStream_t stream) {
  const float* x  = (const float*)d_in[0];
  const int*   ei = (const int*)d_in[1];
  const float* W1 = (const float*)d_in[2];
  const float* b1 = (const float*)d_in[3];
  const float* W2 = (const float*)d_in[4];
  const float* b2 = (const float*)d_in[5];
  float* outp = (float*)d_out;

  int Nn = in_sizes[0] / IN_C;
  int E  = in_sizes[1] / 2;
  const int* srcv = ei;
  const int* dstv = ei + E;

  char* ws = (char*)d_ws;
  size_t o = 0;
  auto alloc = [&](size_t bytes) {
    char* p = ws + o;
    o = (o + bytes + 255) & ~(size_t)255;
    return p;
  };
  float*  dinv  = (float*)alloc((size_t)Nn * 4);
  int*    counts= (int*)alloc((size_t)Nn * 4);
  int*    offs  = (int*)alloc((size_t)(Nn + 1) * 4);
  int*    cur   = (int*)alloc((size_t)Nn * 4);
  int*    adj   = (int*)alloc((size_t)E * 4);
  int*    partial=(int*)alloc((size_t)((Nn + SCAN_TILE - 1) / SCAN_TILE) * 4);
  ushort* W1t   = (ushort*)alloc((size_t)IN_C * HID_C * 2);
  ushort* W2t   = (ushort*)alloc((size_t)HID_C * OUT_C * 2);
  ushort* h1p   = (ushort*)alloc((size_t)Nn * HID_C * 2);
  ushort* h1a   = (ushort*)alloc((size_t)Nn * HID_C * 2);
  ushort* h2p   = (ushort*)alloc((size_t)Nn * OUT_C * 2);
  size_t xb_bytes = (size_t)Nn * IN_C * 2;
  bool use_bf = (o + xb_bytes) <= ws_size;
  ushort* xb = use_bf ? (ushort*)alloc(xb_bytes) : nullptr;

  int eb = (E + 255) / 256;
  int sb = (Nn + SCAN_TILE - 1) / SCAN_TILE;

  hipMemsetAsync(counts, 0, (size_t)Nn * 4, stream);
  deg_count<<<eb, 256, 0, stream>>>(dstv, counts, E);
  scan_block_sums<<<sb, 256, 0, stream>>>(counts, partial, Nn);
  scan_partials<<<1, 64, 0, stream>>>(partial, sb);
  scan_write<<<sb, 256, 0, stream>>>(counts, partial, offs, cur, dinv, Nn, E);
  fill_adj<<<eb, 256, 0, stream>>>(srcv, dstv, cur, adj, E);
  convert_wt<<<(IN_C * HID_C + 255) / 256, 256, 0, stream>>>(W1, W1t, IN_C, HID_C);
  convert_wt<<<(HID_C * OUT_C + 255) / 256, 256, 0, stream>>>(W2, W2t, HID_C, OUT_C);

  if (use_bf) {
    long n8 = (long)Nn * IN_C / 8;
    int cb = (int)((n8 + 255) / 256); if (cb > 2048) cb = 2048;
    convert_x<<<cb, 256, 0, stream>>>(x, xb, n8);
    gemm1_bf<<<dim3((Nn + 127) / 128, HID_C / 128), 256, 0, stream>>>(xb, W1t, dinv, h1p, Nn);
  } else {
    gemm1_f32<<<dim3((Nn + 127) / 128, HID_C / 128), 256, 0, stream>>>(x, W1t, dinv, h1p, Nn);
  }
  agg1<<<(Nn + 3) / 4, 256, 0, stream>>>(h1p, h1a, dinv, offs, adj, b1, Nn);
  gemm2<<<(Nn + 127) / 128, 256, 0, stream>>>(h1a, W2t, dinv, h2p, Nn);
  agg2<<<(Nn + 3) / 4, 256, 0, stream>>>(h2p, outp, dinv, offs, adj, b2, Nn);
}

// Round 7
// 255.623 us; speedup vs baseline: 2.0360x; 1.0057x over previous
//
#include <hip/hip_runtime.h>
#include <hip/hip_bf16.h>

#define IN_C 512
#define HID_C 256
#define OUT_C 64

typedef __attribute__((ext_vector_type(8))) short bf16x8;
typedef __attribute__((ext_vector_type(4))) float f32x4;
typedef __attribute__((ext_vector_type(2))) float f32x2;

__device__ __forceinline__ ushort f2bf(float f) {
  __hip_bfloat16 h = __float2bfloat16(f);
  union { __hip_bfloat16 h; ushort u; } v; v.h = h; return v.u;
}
__device__ __forceinline__ float u2f(uint u) {
  union { uint i; float f; } v; v.i = u; return v.f;
}
// packed accumulate of 4 bf16 {lo0,hi0,lo1,hi1} in (ux,uy) — exact bf16 values.
__device__ __forceinline__ void pkacc(f32x2& aLo, f32x2& aHi, uint ux, uint uy) {
  f32x2 lo, hi;
  lo[0] = u2f(ux << 16);         lo[1] = u2f(uy << 16);
  hi[0] = u2f(ux & 0xffff0000u); hi[1] = u2f(uy & 0xffff0000u);
  aLo += lo;   // v_pk_add_f32
  aHi += hi;
}
// async global->LDS, 16B per lane. LDS dest must be linear (base + lane*16).
__device__ __forceinline__ void glds16(const ushort* g, ushort* l) {
  __builtin_amdgcn_global_load_lds(
      (const __attribute__((address_space(1))) unsigned int*)(const void*)g,
      (__attribute__((address_space(3))) unsigned int*)(void*)l, 16, 0, 0);
}

// ---------------- graph preprocessing ----------------

__global__ void deg_count(const int* __restrict__ dst, int* __restrict__ counts, int E) {
  int e = blockIdx.x * 256 + threadIdx.x;
  if (e >= E) return;
  atomicAdd(&counts[dst[e]], 1);
}

#define SCAN_TILE 1024

__global__ __launch_bounds__(256) void scan_block_sums(const int* __restrict__ counts,
                                                       int* __restrict__ partial, int n) {
  int base = blockIdx.x * SCAN_TILE + threadIdx.x * 4;
  int s = 0;
  if (base + 3 < n) {
    int4 v = *(const int4*)(counts + base);
    s = v.x + v.y + v.z + v.w;
  } else {
#pragma unroll
    for (int i = 0; i < 4; ++i) if (base + i < n) s += counts[base + i];
  }
#pragma unroll
  for (int off = 1; off < 64; off <<= 1) s += __shfl_xor(s, off);
  __shared__ int ws[4];
  int lane = threadIdx.x & 63, wid = threadIdx.x >> 6;
  if (lane == 0) ws[wid] = s;
  __syncthreads();
  if (threadIdx.x == 0) partial[blockIdx.x] = ws[0] + ws[1] + ws[2] + ws[3];
}

__global__ void scan_partials(int* __restrict__ partial, int nb) {
  int lane = threadIdx.x;
  int carry = 0;
  for (int base = 0; base < nb; base += 64) {
    int i = base + lane;
    int v = (i < nb) ? partial[i] : 0;
    int incl = v;
#pragma unroll
    for (int off = 1; off < 64; off <<= 1) {
      int y = __shfl_up(incl, off);
      if (lane >= off) incl += y;
    }
    if (i < nb) partial[i] = carry + incl - v;
    carry += __shfl(incl, 63);
  }
}

__global__ __launch_bounds__(256) void scan_write(const int* __restrict__ counts,
                                                  const int* __restrict__ partial,
                                                  int* __restrict__ offs,
                                                  int* __restrict__ cur,
                                                  float* __restrict__ dinv,
                                                  int n, int E) {
  int tid = threadIdx.x;
  int base = blockIdx.x * SCAN_TILE + tid * 4;
  int4 c = make_int4(0, 0, 0, 0);
  if (base + 3 < n) {
    c = *(const int4*)(counts + base);
  } else {
    if (base + 0 < n) c.x = counts[base + 0];
    if (base + 1 < n) c.y = counts[base + 1];
    if (base + 2 < n) c.z = counts[base + 2];
  }
  int tsum = c.x + c.y + c.z + c.w;
  int lane = tid & 63, wid = tid >> 6;
  int incl = tsum;
#pragma unroll
  for (int off = 1; off < 64; off <<= 1) {
    int y = __shfl_up(incl, off);
    if (lane >= off) incl += y;
  }
  __shared__ int ws[4];
  if (lane == 63) ws[wid] = incl;
  __syncthreads();
  int wbase = 0;
#pragma unroll
  for (int w = 0; w < 4; ++w) if (w < wid) wbase += ws[w];
  int off0 = partial[blockIdx.x] + wbase + (incl - tsum);
  int4 ov;
  ov.x = off0;
  ov.y = off0 + c.x;
  ov.z = off0 + c.x + c.y;
  ov.w = off0 + c.x + c.y + c.z;
  float4 dv;
  dv.x = rsqrtf((float)(c.x + 1));
  dv.y = rsqrtf((float)(c.y + 1));
  dv.z = rsqrtf((float)(c.z + 1));
  dv.w = rsqrtf((float)(c.w + 1));
  if (base + 3 < n) {
    *(int4*)(offs + base) = ov;
    *(int4*)(cur + base) = ov;
    *(float4*)(dinv + base) = dv;
  } else {
    int o4[4] = {ov.x, ov.y, ov.z, ov.w};
    float d4[4] = {dv.x, dv.y, dv.z, dv.w};
    for (int i = 0; i < 4; ++i)
      if (base + i < n) { offs[base + i] = o4[i]; cur[base + i] = o4[i]; dinv[base + i] = d4[i]; }
  }
  if (blockIdx.x == 0 && tid == 0) offs[n] = E;
}

__global__ void fill_adj(const int* __restrict__ src, const int* __restrict__ dst,
                         int* __restrict__ cur, int* __restrict__ adj, int E) {
  int e = blockIdx.x * 256 + threadIdx.x;
  if (e >= E) return;
  int pos = atomicAdd(&cur[dst[e]], 1);
  adj[pos] = src[e];
}

__global__ void convert_wt(const float* __restrict__ W, ushort* __restrict__ Wt, int K, int Ncol) {
  int idx = blockIdx.x * 256 + threadIdx.x;
  if (idx >= K * Ncol) return;
  int n = idx / K, k = idx % K;
  Wt[idx] = f2bf(W[(size_t)k * Ncol + n]);
}

__global__ __launch_bounds__(256) void convert_x(const float* __restrict__ x,
                                                 ushort* __restrict__ xb, long n8) {
  long stride = (long)gridDim.x * 256;
  for (long i = (long)blockIdx.x * 256 + threadIdx.x; i < n8; i += stride) {
    const float4* p = (const float4*)(x + i * 8);
    float4 v0 = p[0], v1 = p[1];
    uint4 o;
    o.x = (uint)f2bf(v0.x) | ((uint)f2bf(v0.y) << 16);
    o.y = (uint)f2bf(v0.z) | ((uint)f2bf(v0.w) << 16);
    o.z = (uint)f2bf(v1.x) | ((uint)f2bf(v1.y) << 16);
    o.w = (uint)f2bf(v1.z) | ((uint)f2bf(v1.w) << 16);
    *(uint4*)(xb + i * 8) = o;
  }
}

// ---------------- GEMMs (2-phase global_load_lds template) ----------------

__global__ __launch_bounds__(256) void gemm1_bf(const ushort* __restrict__ A,
                                                const ushort* __restrict__ Bt,
                                                const float* __restrict__ dinv,
                                                ushort* __restrict__ C, int M) {
  __shared__ __align__(16) ushort As[2][128 * 32];
  __shared__ __align__(16) ushort Bs[2][128 * 32];
  int tid = threadIdx.x;
  int lane = tid & 63, wid = tid >> 6;
  int m0 = blockIdx.x * 128;
  int n0 = blockIdx.y * 128;
  int ca = wid * 64 + lane;
  int rowa0 = ca >> 2, cola0 = (ca & 3) * 8;
  int rowa1 = (ca + 256) >> 2, cola1 = (ca & 3) * 8;
  int gma0 = m0 + rowa0; if (gma0 >= M) gma0 = M - 1;
  int gma1 = m0 + rowa1; if (gma1 >= M) gma1 = M - 1;
  const ushort* gA0 = A + (size_t)gma0 * IN_C + cola0;
  const ushort* gA1 = A + (size_t)gma1 * IN_C + cola1;
  const ushort* gB0 = Bt + (size_t)(n0 + rowa0) * IN_C + cola0;
  const ushort* gB1 = Bt + (size_t)(n0 + rowa1) * IN_C + cola1;

  int wm = (wid >> 1) * 64, wn = (wid & 1) * 64;
  int kf = (lane >> 4) * 8, rl = lane & 15;
  f32x4 acc[4][4] = {};

  glds16(gA0, &As[0][ca * 8]);
  glds16(gA1, &As[0][ca * 8 + 2048]);
  glds16(gB0, &Bs[0][ca * 8]);
  glds16(gB1, &Bs[0][ca * 8 + 2048]);
  __syncthreads();

  int cur = 0;
  for (int t = 0; t < 16; ++t) {
    if (t < 15) {
      int k0 = (t + 1) * 32;
      int nxt = cur ^ 1;
      glds16(gA0 + k0, &As[nxt][ca * 8]);
      glds16(gA1 + k0, &As[nxt][ca * 8 + 2048]);
      glds16(gB0 + k0, &Bs[nxt][ca * 8]);
      glds16(gB1 + k0, &Bs[nxt][ca * 8 + 2048]);
    }
    bf16x8 a[4], b[4];
#pragma unroll
    for (int i = 0; i < 4; ++i)
      a[i] = *(const bf16x8*)&As[cur][(wm + i * 16 + rl) * 32 + kf];
#pragma unroll
    for (int j = 0; j < 4; ++j)
      b[j] = *(const bf16x8*)&Bs[cur][(wn + j * 16 + rl) * 32 + kf];
#pragma unroll
    for (int i = 0; i < 4; ++i)
#pragma unroll
      for (int j = 0; j < 4; ++j)
        acc[i][j] = __builtin_amdgcn_mfma_f32_16x16x32_bf16(a[i], b[j], acc[i][j], 0, 0, 0);
    __syncthreads();
    cur ^= 1;
  }

  int r4 = (lane >> 4) * 4;
  int cl = lane & 15;
#pragma unroll
  for (int i = 0; i < 4; ++i) {
#pragma unroll
    for (int r = 0; r < 4; ++r) {
      int gr = m0 + wm + i * 16 + r4 + r;
      if (gr < M) {
        float dv = dinv[gr];
#pragma unroll
        for (int j = 0; j < 4; ++j) {
          int gc = n0 + wn + j * 16 + cl;
          C[(size_t)gr * HID_C + gc] = f2bf(dv * acc[i][j][r]);
        }
      }
    }
  }
}

__global__ __launch_bounds__(256) void gemm2(const ushort* __restrict__ A,
                                             const ushort* __restrict__ Bt,
                                             const float* __restrict__ dinv,
                                             ushort* __restrict__ C, int M) {
  __shared__ __align__(16) ushort As[2][128 * 32];
  __shared__ __align__(16) ushort Bs[2][64 * 32];
  int tid = threadIdx.x;
  int lane = tid & 63, wid = tid >> 6;
  int m0 = blockIdx.x * 128;
  int ca = wid * 64 + lane;
  int rowa0 = ca >> 2, cola0 = (ca & 3) * 8;
  int rowa1 = (ca + 256) >> 2;
  int gma0 = m0 + rowa0; if (gma0 >= M) gma0 = M - 1;
  int gma1 = m0 + rowa1; if (gma1 >= M) gma1 = M - 1;
  const ushort* gA0 = A + (size_t)gma0 * HID_C + cola0;
  const ushort* gA1 = A + (size_t)gma1 * HID_C + cola0;
  const ushort* gB0 = Bt + (size_t)rowa0 * HID_C + cola0;

  int wm = wid * 32;
  int kf = (lane >> 4) * 8, rl = lane & 15;
  f32x4 acc[2][4] = {};

  glds16(gA0, &As[0][ca * 8]);
  glds16(gA1, &As[0][ca * 8 + 2048]);
  glds16(gB0, &Bs[0][ca * 8]);
  __syncthreads();

  int cur = 0;
  for (int t = 0; t < 8; ++t) {
    if (t < 7) {
      int k0 = (t + 1) * 32;
      int nxt = cur ^ 1;
      glds16(gA0 + k0, &As[nxt][ca * 8]);
      glds16(gA1 + k0, &As[nxt][ca * 8 + 2048]);
      glds16(gB0 + k0, &Bs[nxt][ca * 8]);
    }
    bf16x8 a[2], b[4];
#pragma unroll
    for (int i = 0; i < 2; ++i)
      a[i] = *(const bf16x8*)&As[cur][(wm + i * 16 + rl) * 32 + kf];
#pragma unroll
    for (int j = 0; j < 4; ++j)
      b[j] = *(const bf16x8*)&Bs[cur][(j * 16 + rl) * 32 + kf];
#pragma unroll
    for (int i = 0; i < 2; ++i)
#pragma unroll
      for (int j = 0; j < 4; ++j)
        acc[i][j] = __builtin_amdgcn_mfma_f32_16x16x32_bf16(a[i], b[j], acc[i][j], 0, 0, 0);
    __syncthreads();
    cur ^= 1;
  }

  int r4 = (lane >> 4) * 4;
  int cl = lane & 15;
#pragma unroll
  for (int i = 0; i < 2; ++i) {
#pragma unroll
    for (int r = 0; r < 4; ++r) {
      int gr = m0 + wm + i * 16 + r4 + r;
      if (gr < M) {
        float dv = dinv[gr];
#pragma unroll
        for (int j = 0; j < 4; ++j) {
          int gc = j * 16 + cl;
          C[(size_t)gr * OUT_C + gc] = f2bf(dv * acc[i][j][r]);
        }
      }
    }
  }
}

// ---------------- aggregation ----------------

// one wave per node; adj batch preloaded by all 64 lanes, broadcast via shfl.
// Inner loop has WAVE-UNIFORM trip count: every lane executes every __shfl
// (source lane always active); accumulate predicated by k < bn.
__global__ __launch_bounds__(256) void agg1(const ushort* __restrict__ h,
                                            ushort* __restrict__ out,
                                            const float* __restrict__ dinv,
                                            const int* __restrict__ offs,
                                            const int* __restrict__ adj,
                                            const float* __restrict__ bias, int Nn) {
  int node = blockIdx.x * 4 + (threadIdx.x >> 6);
  if (node >= Nn) return;
  int lane = threadIdx.x & 63;
  int slot = lane >> 4;
  int c0 = (lane & 15) * 16;
  int e0 = offs[node];
  int cnt = offs[node + 1] - e0 + 1;  // virtual edge 0 = self
  const ushort* hc = h + c0;
  f32x2 aLo[4] = {}, aHi[4] = {};
  for (int b0 = 0; b0 < cnt; b0 += 64) {
    int vk = b0 + lane;
    int myadj = node;
    if (vk > 0 && vk < cnt) myadj = adj[e0 + vk - 1];
    int bn = cnt - b0; if (bn > 64) bn = 64;
    int iters = (bn + 3) >> 2;  // uniform across the wave
#pragma unroll 2
    for (int i = 0; i < iters; ++i) {
      int k = slot + 4 * i;
      int s = __shfl(myadj, k < bn ? k : 0);
      if (k < bn) {
        const uint4* rp = (const uint4*)(hc + (size_t)s * HID_C);
        uint4 u0 = rp[0];
        uint4 u1 = rp[1];
        pkacc(aLo[0], aHi[0], u0.x, u0.y);
        pkacc(aLo[1], aHi[1], u0.z, u0.w);
        pkacc(aLo[2], aHi[2], u1.x, u1.y);
        pkacc(aLo[3], aHi[3], u1.z, u1.w);
      }
    }
  }
  // channel map: quad q covers c0+4q..c0+4q+3 as {aLo.x, aHi.x, aLo.y, aHi.y}
  float r16[16];
#pragma unroll
  for (int q = 0; q < 4; ++q) {
    r16[4 * q + 0] = aLo[q][0];
    r16[4 * q + 1] = aHi[q][0];
    r16[4 * q + 2] = aLo[q][1];
    r16[4 * q + 3] = aHi[q][1];
  }
#pragma unroll
  for (int i = 0; i < 16; ++i) {
    r16[i] += __shfl_xor(r16[i], 16);
    r16[i] += __shfl_xor(r16[i], 32);
  }
  if (lane < 16) {
    float dv = dinv[node];
    const float4* bp = (const float4*)(bias + c0);
    float bb[16];
#pragma unroll
    for (int q = 0; q < 4; ++q) {
      float4 b4 = bp[q];
      bb[q * 4 + 0] = b4.x; bb[q * 4 + 1] = b4.y;
      bb[q * 4 + 2] = b4.z; bb[q * 4 + 3] = b4.w;
    }
    uint r[8];
#pragma unroll
    for (int i = 0; i < 8; ++i) {
      float v0 = fmaxf(dv * r16[2 * i]     + bb[2 * i],     0.f);
      float v1 = fmaxf(dv * r16[2 * i + 1] + bb[2 * i + 1], 0.f);
      r[i] = (uint)f2bf(v0) | ((uint)f2bf(v1) << 16);
    }
    uint4* op = (uint4*)(out + (size_t)node * HID_C + c0);
    op[0] = make_uint4(r[0], r[1], r[2], r[3]);
    op[1] = make_uint4(r[4], r[5], r[6], r[7]);
  }
}

// one wave per node; 8 edge slots x 8 lanes x 16B; uniform trip count.
__global__ __launch_bounds__(256) void agg2(const ushort* __restrict__ h,
                                            float* __restrict__ out,
                                            const float* __restrict__ dinv,
                                            const int* __restrict__ offs,
                                            const int* __restrict__ adj,
                                            const float* __restrict__ bias, int Nn) {
  int node = blockIdx.x * 4 + (threadIdx.x >> 6);
  if (node >= Nn) return;
  int lane = threadIdx.x & 63;
  int slot = lane >> 3;
  int c0 = (lane & 7) * 8;
  int e0 = offs[node];
  int cnt = offs[node + 1] - e0 + 1;
  const ushort* hc = h + c0;
  f32x2 aLo[2] = {}, aHi[2] = {};
  for (int b0 = 0; b0 < cnt; b0 += 64) {
    int vk = b0 + lane;
    int myadj = node;
    if (vk > 0 && vk < cnt) myadj = adj[e0 + vk - 1];
    int bn = cnt - b0; if (bn > 64) bn = 64;
    int iters = (bn + 7) >> 3;  // uniform across the wave
#pragma unroll 2
    for (int i = 0; i < iters; ++i) {
      int k = slot + 8 * i;
      int s = __shfl(myadj, k < bn ? k : 0);
      if (k < bn) {
        uint4 u = *(const uint4*)(hc + (size_t)s * OUT_C);
        pkacc(aLo[0], aHi[0], u.x, u.y);
        pkacc(aLo[1], aHi[1], u.z, u.w);
      }
    }
  }
  float r8[8];
#pragma unroll
  for (int q = 0; q < 2; ++q) {
    r8[4 * q + 0] = aLo[q][0];
    r8[4 * q + 1] = aHi[q][0];
    r8[4 * q + 2] = aLo[q][1];
    r8[4 * q + 3] = aHi[q][1];
  }
#pragma unroll
  for (int i = 0; i < 8; ++i) {
    r8[i] += __shfl_xor(r8[i], 8);
    r8[i] += __shfl_xor(r8[i], 16);
    r8[i] += __shfl_xor(r8[i], 32);
  }
  float dv = dinv[node];
  const float4* bp = (const float4*)(bias + c0);
  float4 bb0 = bp[0], bb1 = bp[1];
  float v[8];
  v[0] = dv * r8[0] + bb0.x; v[1] = dv * r8[1] + bb0.y;
  v[2] = dv * r8[2] + bb0.z; v[3] = dv * r8[3] + bb0.w;
  v[4] = dv * r8[4] + bb1.x; v[5] = dv * r8[5] + bb1.y;
  v[6] = dv * r8[6] + bb1.z; v[7] = dv * r8[7] + bb1.w;
  float m = v[0];
#pragma unroll
  for (int i = 1; i < 8; ++i) m = fmaxf(m, v[i]);
  m = fmaxf(m, __shfl_xor(m, 1));
  m = fmaxf(m, __shfl_xor(m, 2));
  m = fmaxf(m, __shfl_xor(m, 4));
  float s8 = 0.f;
#pragma unroll
  for (int i = 0; i < 8; ++i) s8 += expf(v[i] - m);
  s8 += __shfl_xor(s8, 1);
  s8 += __shfl_xor(s8, 2);
  s8 += __shfl_xor(s8, 4);
  float lg = logf(s8);
  if (lane < 8) {
    float4* op = (float4*)(out + (size_t)node * OUT_C + c0);
    op[0] = make_float4(v[0] - m - lg, v[1] - m - lg, v[2] - m - lg, v[3] - m - lg);
    op[1] = make_float4(v[4] - m - lg, v[5] - m - lg, v[6] - m - lg, v[7] - m - lg);
  }
}

// ---------------- launch ----------------

extern "C" void kernel_launch(void* const* d_in, const int* in_sizes, int n_in,
                              void* d_out, int out_size, void* d_ws, size_t ws_size,
                              hipStream_t stream) {
  const float* x  = (const float*)d_in[0];
  const int*   ei = (const int*)d_in[1];
  const float* W1 = (const float*)d_in[2];
  const float* b1 = (const float*)d_in[3];
  const float* W2 = (const float*)d_in[4];
  const float* b2 = (const float*)d_in[5];
  float* outp = (float*)d_out;

  int Nn = in_sizes[0] / IN_C;
  int E  = in_sizes[1] / 2;
  const int* srcv = ei;
  const int* dstv = ei + E;

  char* ws = (char*)d_ws;
  size_t o = 0;
  auto alloc = [&](size_t bytes) {
    char* p = ws + o;
    o = (o + bytes + 255) & ~(size_t)255;
    return p;
  };
  float*  dinv  = (float*)alloc((size_t)Nn * 4);
  int*    counts= (int*)alloc((size_t)Nn * 4);
  int*    offs  = (int*)alloc((size_t)(Nn + 1) * 4);
  int*    cur   = (int*)alloc((size_t)Nn * 4);
  int*    adj   = (int*)alloc((size_t)E * 4);
  int*    partial=(int*)alloc((size_t)((Nn + SCAN_TILE - 1) / SCAN_TILE) * 4);
  ushort* W1t   = (ushort*)alloc((size_t)IN_C * HID_C * 2);
  ushort* W2t   = (ushort*)alloc((size_t)HID_C * OUT_C * 2);
  ushort* h1p   = (ushort*)alloc((size_t)Nn * HID_C * 2);
  ushort* h1a   = (ushort*)alloc((size_t)Nn * HID_C * 2);
  ushort* h2p   = (ushort*)alloc((size_t)Nn * OUT_C * 2);
  size_t xb_bytes = (size_t)Nn * IN_C * 2;
  bool use_bf = (o + xb_bytes) <= ws_size;
  ushort* xb = use_bf ? (ushort*)alloc(xb_bytes) : nullptr;

  int eb = (E + 255) / 256;
  int sb = (Nn + SCAN_TILE - 1) / SCAN_TILE;

  hipMemsetAsync(counts, 0, (size_t)Nn * 4, stream);
  deg_count<<<eb, 256, 0, stream>>>(dstv, counts, E);
  scan_block_sums<<<sb, 256, 0, stream>>>(counts, partial, Nn);
  scan_partials<<<1, 64, 0, stream>>>(partial, sb);
  scan_write<<<sb, 256, 0, stream>>>(counts, partial, offs, cur, dinv, Nn, E);
  fill_adj<<<eb, 256, 0, stream>>>(srcv, dstv, cur, adj, E);
  convert_wt<<<(IN_C * HID_C + 255) / 256, 256, 0, stream>>>(W1, W1t, IN_C, HID_C);
  convert_wt<<<(HID_C * OUT_C + 255) / 256, 256, 0, stream>>>(W2, W2t, HID_C, OUT_C);

  if (use_bf) {
    long n8 = (long)Nn * IN_C / 8;
    int cb = (int)((n8 + 255) / 256); if (cb > 2048) cb = 2048;
    convert_x<<<cb, 256, 0, stream>>>(x, xb, n8);
    gemm1_bf<<<dim3((Nn + 127) / 128, HID_C / 128), 256, 0, stream>>>(xb, W1t, dinv, h1p, Nn);
  } else {
    gemm1_bf<<<dim3((Nn + 127) / 128, HID_C / 128), 256, 0, stream>>>((const ushort*)x, W1t, dinv, h1p, Nn);
  }
  agg1<<<(Nn + 3) / 4, 256, 0, stream>>>(h1p, h1a, dinv, offs, adj, b1, Nn);
  gemm2<<<(Nn + 127) / 128, 256, 0, stream>>>(h1a, W2t, dinv, h2p, Nn);
  agg2<<<(Nn + 3) / 4, 256, 0, stream>>>(h2p, outp, dinv, offs, adj, b2, Nn);
}

// Round 8
// 231.722 us; speedup vs baseline: 2.2460x; 1.1031x over previous
//
#include <hip/hip_runtime.h>
#include <hip/hip_bf16.h>

#define IN_C 512
#define HID_C 256
#define OUT_C 64

typedef __attribute__((ext_vector_type(8))) short bf16x8;
typedef __attribute__((ext_vector_type(4))) float f32x4;
typedef __attribute__((ext_vector_type(2))) float f32x2;

__device__ __forceinline__ ushort f2bf(float f) {
  __hip_bfloat16 h = __float2bfloat16(f);
  union { __hip_bfloat16 h; ushort u; } v; v.h = h; return v.u;
}
__device__ __forceinline__ uint pack2bf(float a, float b) {
  return (uint)f2bf(a) | ((uint)f2bf(b) << 16);
}
__device__ __forceinline__ float u2f(uint u) {
  union { uint i; float f; } v; v.i = u; return v.f;
}
// packed accumulate of 4 bf16 {lo0,hi0,lo1,hi1} in (ux,uy) — exact bf16 values.
__device__ __forceinline__ void pkacc(f32x2& aLo, f32x2& aHi, uint ux, uint uy) {
  f32x2 lo, hi;
  lo[0] = u2f(ux << 16);         lo[1] = u2f(uy << 16);
  hi[0] = u2f(ux & 0xffff0000u); hi[1] = u2f(uy & 0xffff0000u);
  aLo += lo;   // v_pk_add_f32
  aHi += hi;
}
// async global->LDS, 16B per lane. LDS dest must be linear (base + lane*16).
__device__ __forceinline__ void glds16(const ushort* g, ushort* l) {
  __builtin_amdgcn_global_load_lds(
      (const __attribute__((address_space(1))) unsigned int*)(const void*)g,
      (__attribute__((address_space(3))) unsigned int*)(void*)l, 16, 0, 0);
}

// ---------------- graph preprocessing ----------------

__global__ void deg_count(const int* __restrict__ dst, int* __restrict__ counts, int E) {
  int e = blockIdx.x * 256 + threadIdx.x;
  if (e >= E) return;
  atomicAdd(&counts[dst[e]], 1);
}

#define SCAN_TILE 1024

__global__ __launch_bounds__(256) void scan_block_sums(const int* __restrict__ counts,
                                                       int* __restrict__ partial, int n) {
  int base = blockIdx.x * SCAN_TILE + threadIdx.x * 4;
  int s = 0;
  if (base + 3 < n) {
    int4 v = *(const int4*)(counts + base);
    s = v.x + v.y + v.z + v.w;
  } else {
#pragma unroll
    for (int i = 0; i < 4; ++i) if (base + i < n) s += counts[base + i];
  }
#pragma unroll
  for (int off = 1; off < 64; off <<= 1) s += __shfl_xor(s, off);
  __shared__ int ws[4];
  int lane = threadIdx.x & 63, wid = threadIdx.x >> 6;
  if (lane == 0) ws[wid] = s;
  __syncthreads();
  if (threadIdx.x == 0) partial[blockIdx.x] = ws[0] + ws[1] + ws[2] + ws[3];
}

__global__ void scan_partials(int* __restrict__ partial, int nb) {
  int lane = threadIdx.x;
  int carry = 0;
  for (int base = 0; base < nb; base += 64) {
    int i = base + lane;
    int v = (i < nb) ? partial[i] : 0;
    int incl = v;
#pragma unroll
    for (int off = 1; off < 64; off <<= 1) {
      int y = __shfl_up(incl, off);
      if (lane >= off) incl += y;
    }
    if (i < nb) partial[i] = carry + incl - v;
    carry += __shfl(incl, 63);
  }
}

__global__ __launch_bounds__(256) void scan_write(const int* __restrict__ counts,
                                                  const int* __restrict__ partial,
                                                  int* __restrict__ offs,
                                                  int* __restrict__ cur,
                                                  float* __restrict__ dinv,
                                                  int n, int E) {
  int tid = threadIdx.x;
  int base = blockIdx.x * SCAN_TILE + tid * 4;
  int4 c = make_int4(0, 0, 0, 0);
  if (base + 3 < n) {
    c = *(const int4*)(counts + base);
  } else {
    if (base + 0 < n) c.x = counts[base + 0];
    if (base + 1 < n) c.y = counts[base + 1];
    if (base + 2 < n) c.z = counts[base + 2];
  }
  int tsum = c.x + c.y + c.z + c.w;
  int lane = tid & 63, wid = tid >> 6;
  int incl = tsum;
#pragma unroll
  for (int off = 1; off < 64; off <<= 1) {
    int y = __shfl_up(incl, off);
    if (lane >= off) incl += y;
  }
  __shared__ int ws[4];
  if (lane == 63) ws[wid] = incl;
  __syncthreads();
  int wbase = 0;
#pragma unroll
  for (int w = 0; w < 4; ++w) if (w < wid) wbase += ws[w];
  int off0 = partial[blockIdx.x] + wbase + (incl - tsum);
  int4 ov;
  ov.x = off0;
  ov.y = off0 + c.x;
  ov.z = off0 + c.x + c.y;
  ov.w = off0 + c.x + c.y + c.z;
  float4 dv;
  dv.x = rsqrtf((float)(c.x + 1));
  dv.y = rsqrtf((float)(c.y + 1));
  dv.z = rsqrtf((float)(c.z + 1));
  dv.w = rsqrtf((float)(c.w + 1));
  if (base + 3 < n) {
    *(int4*)(offs + base) = ov;
    *(int4*)(cur + base) = ov;
    *(float4*)(dinv + base) = dv;
  } else {
    int o4[4] = {ov.x, ov.y, ov.z, ov.w};
    float d4[4] = {dv.x, dv.y, dv.z, dv.w};
    for (int i = 0; i < 4; ++i)
      if (base + i < n) { offs[base + i] = o4[i]; cur[base + i] = o4[i]; dinv[base + i] = d4[i]; }
  }
  if (blockIdx.x == 0 && tid == 0) offs[n] = E;
}

__global__ void fill_adj(const int* __restrict__ src, const int* __restrict__ dst,
                         int* __restrict__ cur, int* __restrict__ adj, int E) {
  int e = blockIdx.x * 256 + threadIdx.x;
  if (e >= E) return;
  int pos = atomicAdd(&cur[dst[e]], 1);
  adj[pos] = src[e];
}

// W[K][N] fp32 -> Wt[N][K] bf16, 32x32 LDS-tiled, coalesced both sides.
__global__ __launch_bounds__(256) void transpose_w(const float* __restrict__ W,
                                                   ushort* __restrict__ Wt, int K, int N) {
  __shared__ ushort t[32][33];
  int n0 = blockIdx.x * 32;
  int k0 = blockIdx.y * 32;
  int tx = threadIdx.x & 31;
  int ty = threadIdx.x >> 5;  // 0..7
#pragma unroll
  for (int i = 0; i < 4; ++i) {
    int k = k0 + ty + i * 8;
    t[ty + i * 8][tx] = f2bf(W[(size_t)k * N + n0 + tx]);
  }
  __syncthreads();
#pragma unroll
  for (int i = 0; i < 4; ++i) {
    int n = n0 + ty + i * 8;
    Wt[(size_t)n * K + k0 + tx] = t[tx][ty + i * 8];
  }
}

// ---------------- GEMMs ----------------

// C[M][256] bf16 (pre-scaled by dinv[row]) = A[M][512] fp32 x W1t[256][512] bf16
// Single N-tile (128M x 256N), 512 threads (2x4 waves of 64x64), BK=32.
// A: reg-staged fp32->bf16 (issue-early, cvt+ds_write late); B: glds16. Double-buffered.
__global__ __launch_bounds__(512) void gemm1_fs(const float* __restrict__ A,
                                                const ushort* __restrict__ Bt,
                                                const float* __restrict__ dinv,
                                                ushort* __restrict__ C, int M) {
  __shared__ __align__(16) ushort As[2][128 * 32];
  __shared__ __align__(16) ushort Bs[2][256 * 32];
  int tid = threadIdx.x;
  int lane = tid & 63, wid = tid >> 6;       // wid 0..7
  int m0 = blockIdx.x * 128;
  // A staging: row = tid>>2 (0..127), 8 floats at col (tid&3)*8
  int arow = tid >> 2, acol = (tid & 3) * 8;
  int gma = m0 + arow; if (gma >= M) gma = M - 1;
  const float* gA = A + (size_t)gma * IN_C + acol;
  // B staging: chunk c -> row c>>2 (0..255), col (c&3)*8; this thread: c=tid, c=tid+512
  int rb0 = tid >> 2, cb0 = (tid & 3) * 8;
  int rb1 = (tid + 512) >> 2;
  const ushort* gB0 = Bt + (size_t)rb0 * IN_C + cb0;
  const ushort* gB1 = Bt + (size_t)rb1 * IN_C + cb0;

  int wr = wid >> 2, wc = wid & 3;           // wave tile (wr*64, wc*64)
  int kf = (lane >> 4) * 8, rl = lane & 15;
  f32x4 acc[4][4] = {};

  // prologue: stage t=0
  {
    float4 p0 = *(const float4*)gA;
    float4 p1 = *(const float4*)(gA + 4);
    glds16(gB0, &Bs[0][tid * 8]);
    glds16(gB1, &Bs[0][(tid + 512) * 8]);
    uint4 w;
    w.x = pack2bf(p0.x, p0.y); w.y = pack2bf(p0.z, p0.w);
    w.z = pack2bf(p1.x, p1.y); w.w = pack2bf(p1.z, p1.w);
    *(uint4*)&As[0][arow * 32 + acol] = w;
  }
  __syncthreads();

  int cur = 0;
  for (int t = 0; t < 16; ++t) {
    float4 p0, p1;
    if (t < 15) {
      const float* g = gA + (t + 1) * 32;
      p0 = *(const float4*)g;
      p1 = *(const float4*)(g + 4);
      glds16(gB0 + (t + 1) * 32, &Bs[cur ^ 1][tid * 8]);
      glds16(gB1 + (t + 1) * 32, &Bs[cur ^ 1][(tid + 512) * 8]);
    }
    bf16x8 af[4], bf[4];
#pragma unroll
    for (int i = 0; i < 4; ++i)
      af[i] = *(const bf16x8*)&As[cur][(wr * 64 + i * 16 + rl) * 32 + kf];
#pragma unroll
    for (int j = 0; j < 4; ++j)
      bf[j] = *(const bf16x8*)&Bs[cur][(wc * 64 + j * 16 + rl) * 32 + kf];
#pragma unroll
    for (int i = 0; i < 4; ++i)
#pragma unroll
      for (int j = 0; j < 4; ++j)
        acc[i][j] = __builtin_amdgcn_mfma_f32_16x16x32_bf16(af[i], bf[j], acc[i][j], 0, 0, 0);
    if (t < 15) {
      uint4 w;
      w.x = pack2bf(p0.x, p0.y); w.y = pack2bf(p0.z, p0.w);
      w.z = pack2bf(p1.x, p1.y); w.w = pack2bf(p1.z, p1.w);
      *(uint4*)&As[cur ^ 1][arow * 32 + acol] = w;
    }
    __syncthreads();
    cur ^= 1;
  }

  int r4 = (lane >> 4) * 4;
  int cl = lane & 15;
#pragma unroll
  for (int i = 0; i < 4; ++i) {
#pragma unroll
    for (int r = 0; r < 4; ++r) {
      int gr = m0 + wr * 64 + i * 16 + r4 + r;
      if (gr < M) {
        float dv = dinv[gr];
#pragma unroll
        for (int j = 0; j < 4; ++j) {
          int gc = wc * 64 + j * 16 + cl;
          C[(size_t)gr * HID_C + gc] = f2bf(dv * acc[i][j][r]);
        }
      }
    }
  }
}

// C[M][64] bf16 (pre-scaled) = A[M][256] bf16 x W2t[64][256] bf16
// 128x64 tile, BK=32, double-buffered glds16, prefetch-before-compute.
__global__ __launch_bounds__(256) void gemm2(const ushort* __restrict__ A,
                                             const ushort* __restrict__ Bt,
                                             const float* __restrict__ dinv,
                                             ushort* __restrict__ C, int M) {
  __shared__ __align__(16) ushort As[2][128 * 32];
  __shared__ __align__(16) ushort Bs[2][64 * 32];
  int tid = threadIdx.x;
  int lane = tid & 63, wid = tid >> 6;
  int m0 = blockIdx.x * 128;
  int ca = wid * 64 + lane;
  int rowa0 = ca >> 2, cola0 = (ca & 3) * 8;
  int rowa1 = (ca + 256) >> 2;
  int gma0 = m0 + rowa0; if (gma0 >= M) gma0 = M - 1;
  int gma1 = m0 + rowa1; if (gma1 >= M) gma1 = M - 1;
  const ushort* gA0 = A + (size_t)gma0 * HID_C + cola0;
  const ushort* gA1 = A + (size_t)gma1 * HID_C + cola0;
  const ushort* gB0 = Bt + (size_t)rowa0 * HID_C + cola0;

  int wm = wid * 32;
  int kf = (lane >> 4) * 8, rl = lane & 15;
  f32x4 acc[2][4] = {};

  glds16(gA0, &As[0][ca * 8]);
  glds16(gA1, &As[0][ca * 8 + 2048]);
  glds16(gB0, &Bs[0][ca * 8]);
  __syncthreads();

  int cur = 0;
  for (int t = 0; t < 8; ++t) {
    if (t < 7) {
      int k0 = (t + 1) * 32;
      int nxt = cur ^ 1;
      glds16(gA0 + k0, &As[nxt][ca * 8]);
      glds16(gA1 + k0, &As[nxt][ca * 8 + 2048]);
      glds16(gB0 + k0, &Bs[nxt][ca * 8]);
    }
    bf16x8 a[2], b[4];
#pragma unroll
    for (int i = 0; i < 2; ++i)
      a[i] = *(const bf16x8*)&As[cur][(wm + i * 16 + rl) * 32 + kf];
#pragma unroll
    for (int j = 0; j < 4; ++j)
      b[j] = *(const bf16x8*)&Bs[cur][(j * 16 + rl) * 32 + kf];
#pragma unroll
    for (int i = 0; i < 2; ++i)
#pragma unroll
      for (int j = 0; j < 4; ++j)
        acc[i][j] = __builtin_amdgcn_mfma_f32_16x16x32_bf16(a[i], b[j], acc[i][j], 0, 0, 0);
    __syncthreads();
    cur ^= 1;
  }

  int r4 = (lane >> 4) * 4;
  int cl = lane & 15;
#pragma unroll
  for (int i = 0; i < 2; ++i) {
#pragma unroll
    for (int r = 0; r < 4; ++r) {
      int gr = m0 + wm + i * 16 + r4 + r;
      if (gr < M) {
        float dv = dinv[gr];
#pragma unroll
        for (int j = 0; j < 4; ++j) {
          int gc = j * 16 + cl;
          C[(size_t)gr * OUT_C + gc] = f2bf(dv * acc[i][j][r]);
        }
      }
    }
  }
}

// ---------------- aggregation ----------------

// one wave per node; adj batch preloaded by all 64 lanes, broadcast via shfl.
// WAVE-UNIFORM trip count; accumulate predicated by k < bn.
__global__ __launch_bounds__(256) void agg1(const ushort* __restrict__ h,
                                            ushort* __restrict__ out,
                                            const float* __restrict__ dinv,
                                            const int* __restrict__ offs,
                                            const int* __restrict__ adj,
                                            const float* __restrict__ bias, int Nn) {
  int node = blockIdx.x * 4 + (threadIdx.x >> 6);
  if (node >= Nn) return;
  int lane = threadIdx.x & 63;
  int slot = lane >> 4;
  int c0 = (lane & 15) * 16;
  int e0 = offs[node];
  int cnt = offs[node + 1] - e0 + 1;  // virtual edge 0 = self
  const ushort* hc = h + c0;
  f32x2 aLo[4] = {}, aHi[4] = {};
  for (int b0 = 0; b0 < cnt; b0 += 64) {
    int vk = b0 + lane;
    int myadj = node;
    if (vk > 0 && vk < cnt) myadj = adj[e0 + vk - 1];
    int bn = cnt - b0; if (bn > 64) bn = 64;
    int iters = (bn + 3) >> 2;  // uniform across the wave
#pragma unroll 4
    for (int i = 0; i < iters; ++i) {
      int k = slot + 4 * i;
      int s = __shfl(myadj, k < bn ? k : 0);
      if (k < bn) {
        const uint4* rp = (const uint4*)(hc + (size_t)s * HID_C);
        uint4 u0 = rp[0];
        uint4 u1 = rp[1];
        pkacc(aLo[0], aHi[0], u0.x, u0.y);
        pkacc(aLo[1], aHi[1], u0.z, u0.w);
        pkacc(aLo[2], aHi[2], u1.x, u1.y);
        pkacc(aLo[3], aHi[3], u1.z, u1.w);
      }
    }
  }
  float r16[16];
#pragma unroll
  for (int q = 0; q < 4; ++q) {
    r16[4 * q + 0] = aLo[q][0];
    r16[4 * q + 1] = aHi[q][0];
    r16[4 * q + 2] = aLo[q][1];
    r16[4 * q + 3] = aHi[q][1];
  }
#pragma unroll
  for (int i = 0; i < 16; ++i) {
    r16[i] += __shfl_xor(r16[i], 16);
    r16[i] += __shfl_xor(r16[i], 32);
  }
  if (lane < 16) {
    float dv = dinv[node];
    const float4* bp = (const float4*)(bias + c0);
    float bb[16];
#pragma unroll
    for (int q = 0; q < 4; ++q) {
      float4 b4 = bp[q];
      bb[q * 4 + 0] = b4.x; bb[q * 4 + 1] = b4.y;
      bb[q * 4 + 2] = b4.z; bb[q * 4 + 3] = b4.w;
    }
    uint r[8];
#pragma unroll
    for (int i = 0; i < 8; ++i) {
      float v0 = fmaxf(dv * r16[2 * i]     + bb[2 * i],     0.f);
      float v1 = fmaxf(dv * r16[2 * i + 1] + bb[2 * i + 1], 0.f);
      r[i] = (uint)f2bf(v0) | ((uint)f2bf(v1) << 16);
    }
    uint4* op = (uint4*)(out + (size_t)node * HID_C + c0);
    op[0] = make_uint4(r[0], r[1], r[2], r[3]);
    op[1] = make_uint4(r[4], r[5], r[6], r[7]);
  }
}

// one wave per node; 8 edge slots x 8 lanes x 16B; uniform trip count.
__global__ __launch_bounds__(256) void agg2(const ushort* __restrict__ h,
                                            float* __restrict__ out,
                                            const float* __restrict__ dinv,
                                            const int* __restrict__ offs,
                                            const int* __restrict__ adj,
                                            const float* __restrict__ bias, int Nn) {
  int node = blockIdx.x * 4 + (threadIdx.x >> 6);
  if (node >= Nn) return;
  int lane = threadIdx.x & 63;
  int slot = lane >> 3;
  int c0 = (lane & 7) * 8;
  int e0 = offs[node];
  int cnt = offs[node + 1] - e0 + 1;
  const ushort* hc = h + c0;
  f32x2 aLo[2] = {}, aHi[2] = {};
  for (int b0 = 0; b0 < cnt; b0 += 64) {
    int vk = b0 + lane;
    int myadj = node;
    if (vk > 0 && vk < cnt) myadj = adj[e0 + vk - 1];
    int bn = cnt - b0; if (bn > 64) bn = 64;
    int iters = (bn + 7) >> 3;  // uniform across the wave
#pragma unroll 4
    for (int i = 0; i < iters; ++i) {
      int k = slot + 8 * i;
      int s = __shfl(myadj, k < bn ? k : 0);
      if (k < bn) {
        uint4 u = *(const uint4*)(hc + (size_t)s * OUT_C);
        pkacc(aLo[0], aHi[0], u.x, u.y);
        pkacc(aLo[1], aHi[1], u.z, u.w);
      }
    }
  }
  float r8[8];
#pragma unroll
  for (int q = 0; q < 2; ++q) {
    r8[4 * q + 0] = aLo[q][0];
    r8[4 * q + 1] = aHi[q][0];
    r8[4 * q + 2] = aLo[q][1];
    r8[4 * q + 3] = aHi[q][1];
  }
#pragma unroll
  for (int i = 0; i < 8; ++i) {
    r8[i] += __shfl_xor(r8[i], 8);
    r8[i] += __shfl_xor(r8[i], 16);
    r8[i] += __shfl_xor(r8[i], 32);
  }
  float dv = dinv[node];
  const float4* bp = (const float4*)(bias + c0);
  float4 bb0 = bp[0], bb1 = bp[1];
  float v[8];
  v[0] = dv * r8[0] + bb0.x; v[1] = dv * r8[1] + bb0.y;
  v[2] = dv * r8[2] + bb0.z; v[3] = dv * r8[3] + bb0.w;
  v[4] = dv * r8[4] + bb1.x; v[5] = dv * r8[5] + bb1.y;
  v[6] = dv * r8[6] + bb1.z; v[7] = dv * r8[7] + bb1.w;
  float m = v[0];
#pragma unroll
  for (int i = 1; i < 8; ++i) m = fmaxf(m, v[i]);
  m = fmaxf(m, __shfl_xor(m, 1));
  m = fmaxf(m, __shfl_xor(m, 2));
  m = fmaxf(m, __shfl_xor(m, 4));
  float s8 = 0.f;
#pragma unroll
  for (int i = 0; i < 8; ++i) s8 += expf(v[i] - m);
  s8 += __shfl_xor(s8, 1);
  s8 += __shfl_xor(s8, 2);
  s8 += __shfl_xor(s8, 4);
  float lg = logf(s8);
  if (lane < 8) {
    float4* op = (float4*)(out + (size_t)node * OUT_C + c0);
    op[0] = make_float4(v[0] - m - lg, v[1] - m - lg, v[2] - m - lg, v[3] - m - lg);
    op[1] = make_float4(v[4] - m - lg, v[5] - m - lg, v[6] - m - lg, v[7] - m - lg);
  }
}

// ---------------- launch ----------------

extern "C" void kernel_launch(void* const* d_in, const int* in_sizes, int n_in,
                              void* d_out, int out_size, void* d_ws, size_t ws_size,
                              hipStream_t stream) {
  const float* x  = (const float*)d_in[0];
  const int*   ei = (const int*)d_in[1];
  const float* W1 = (const float*)d_in[2];
  const float* b1 = (const float*)d_in[3];
  const float* W2 = (const float*)d_in[4];
  const float* b2 = (const float*)d_in[5];
  float* outp = (float*)d_out;

  int Nn = in_sizes[0] / IN_C;
  int E  = in_sizes[1] / 2;
  const int* srcv = ei;
  const int* dstv = ei + E;

  char* ws = (char*)d_ws;
  size_t o = 0;
  auto alloc = [&](size_t bytes) {
    char* p = ws + o;
    o = (o + bytes + 255) & ~(size_t)255;
    return p;
  };
  float*  dinv  = (float*)alloc((size_t)Nn * 4);
  int*    counts= (int*)alloc((size_t)Nn * 4);
  int*    offs  = (int*)alloc((size_t)(Nn + 1) * 4);
  int*    cur   = (int*)alloc((size_t)Nn * 4);
  int*    adj   = (int*)alloc((size_t)E * 4);
  int*    partial=(int*)alloc((size_t)((Nn + SCAN_TILE - 1) / SCAN_TILE) * 4);
  ushort* W1t   = (ushort*)alloc((size_t)IN_C * HID_C * 2);
  ushort* W2t   = (ushort*)alloc((size_t)HID_C * OUT_C * 2);
  ushort* h1p   = (ushort*)alloc((size_t)Nn * HID_C * 2);
  ushort* h1a   = (ushort*)alloc((size_t)Nn * HID_C * 2);
  ushort* h2p   = (ushort*)alloc((size_t)Nn * OUT_C * 2);

  int eb = (E + 255) / 256;
  int sb = (Nn + SCAN_TILE - 1) / SCAN_TILE;

  hipMemsetAsync(counts, 0, (size_t)Nn * 4, stream);
  deg_count<<<eb, 256, 0, stream>>>(dstv, counts, E);
  scan_block_sums<<<sb, 256, 0, stream>>>(counts, partial, Nn);
  scan_partials<<<1, 64, 0, stream>>>(partial, sb);
  scan_write<<<sb, 256, 0, stream>>>(counts, partial, offs, cur, dinv, Nn, E);
  fill_adj<<<eb, 256, 0, stream>>>(srcv, dstv, cur, adj, E);
  transpose_w<<<dim3(HID_C / 32, IN_C / 32), 256, 0, stream>>>(W1, W1t, IN_C, HID_C);
  transpose_w<<<dim3(OUT_C / 32, HID_C / 32), 256, 0, stream>>>(W2, W2t, HID_C, OUT_C);

  gemm1_fs<<<(Nn + 127) / 128, 512, 0, stream>>>(x, W1t, dinv, h1p, Nn);
  agg1<<<(Nn + 3) / 4, 256, 0, stream>>>(h1p, h1a, dinv, offs, adj, b1, Nn);
  gemm2<<<(Nn + 127) / 128, 256, 0, stream>>>(h1a, W2t, dinv, h2p, Nn);
  agg2<<<(Nn + 3) / 4, 256, 0, stream>>>(h2p, outp, dinv, offs, adj, b2, Nn);
}